// Round 7
// baseline (2351.525 us; speedup 1.0000x reference)
//
#include <hip/hip_runtime.h>
#include <hip/hip_bf16.h>
#include <math.h>

#define N_ATOMS 50000
#define N_EDGES 1600000
#define FDIM 128
#define NB 25
#define CUTOFF_F 5.0f
#define PI_OVER_CUTOFF 0.6283185307179586f

typedef __bf16 bf16x8 __attribute__((ext_vector_type(8)));
typedef float f32x4 __attribute__((ext_vector_type(4)));

__device__ __forceinline__ float swish_f(float v) {
    return v / (1.0f + __expf(-v));
}

// XOR swizzle on 16B slots.
#define SWZ(row) ((((row) & 7) ^ (((row) >> 3) & 1)) << 4)

// ---------------- sort-by-dst machinery (CSR build) ----------------

__global__ void hist_kernel(const int* __restrict__ dst, int* __restrict__ count) {
    int i = blockIdx.x * 256 + threadIdx.x;
    if (i < N_EDGES) atomicAdd(&count[dst[i]], 1);
}

// Single block, 256 threads, no cross-lane intrinsics (proven in round 5).
// Writes exclusive prefix to BOTH rowstart (kept) and cursor (consumed by scatter).
__global__ __launch_bounds__(256) void scan_simple_kernel(
    const int* __restrict__ count, int* __restrict__ rowstart,
    int* __restrict__ cursor)
{
    __shared__ int ssum[256];
    const int t = threadIdx.x;
    const int CH = (N_ATOMS + 255) / 256;   // 196
    const int lo = t * CH;
    const int hi = (lo + CH < N_ATOMS) ? lo + CH : N_ATOMS;

    int s = 0;
    for (int b = lo; b < hi; ++b) s += count[b];
    ssum[t] = s;
    __syncthreads();

    if (t == 0) {
        int run = 0;
        for (int i = 0; i < 256; ++i) {
            int tmp = ssum[i];
            ssum[i] = run;
            run += tmp;
        }
    }
    __syncthreads();

    int run = ssum[t];
    for (int b = lo; b < hi; ++b) {
        rowstart[b] = run;
        cursor[b] = run;
        run += count[b];
    }
}

__global__ void scatter_kernel(const int* __restrict__ dst, int* __restrict__ cursor,
                               int* __restrict__ perm) {
    int i = blockIdx.x * 256 + threadIdx.x;
    if (i < N_EDGES) {
        int d = dst[i];
        int p = atomicAdd(&cursor[d], 1);
        perm[p] = i;
    }
}

// ---------------- weight packing ----------------

__global__ void pack_b_kernel(const float* __restrict__ W, __bf16* __restrict__ out,
                              int K_eff, int KS)
{
    int idx = blockIdx.x * 256 + threadIdx.x;
    int total = KS * 8 * 64 * 8;
    if (idx >= total) return;
    int j  = idx & 7;
    int l  = (idx >> 3) & 63;
    int n  = (idx >> 9) & 7;
    int ks = idx >> 12;
    int k   = ks * 32 + ((l >> 4) << 3) + j;
    int col = (n << 4) + (l & 15);
    float v = (k < K_eff) ? W[k * FDIM + col] : 0.0f;
    out[idx] = (__bf16)v;
}

// ---------------- node GEMM (fp32 compute) ----------------
// If out_bf != null: write bf16 in PERMUTED layout pos=(col&15)*8+(col>>4).
// Else write f32 row-major to out_f32.

__global__ __launch_bounds__(256, 4) void node_gemm_kernel(
    const float* __restrict__ A, const float* __restrict__ W,
    const float* __restrict__ bias, float* __restrict__ out_f32,
    __bf16* __restrict__ out_bf, int n_rows, int do_swish)
{
    __shared__ float As[32 * 132];
    __shared__ float Ws[16 * 128];

    const int t = threadIdx.x;
    const int row0 = blockIdx.x * 32;
    const int c4 = (t & 31) * 4;
    const int rb = (t >> 5) * 4;

    for (int v = t; v < 1024; v += 256) {
        int r = v >> 5;
        int c = (v & 31) * 4;
        float4 val;
        if (row0 + r < n_rows) val = *(const float4*)&A[(size_t)(row0 + r) * FDIM + c];
        else val = make_float4(0.f, 0.f, 0.f, 0.f);
        *(float4*)&As[r * 132 + c] = val;
    }

    float acc[4][4];
    #pragma unroll
    for (int i = 0; i < 4; ++i)
        #pragma unroll
        for (int j = 0; j < 4; ++j) acc[i][j] = 0.f;

    for (int k0 = 0; k0 < 128; k0 += 16) {
        __syncthreads();
        for (int v = t; v < 512; v += 256)
            *(float4*)&Ws[v * 4] = *(const float4*)&W[k0 * 128 + v * 4];
        __syncthreads();
        #pragma unroll
        for (int kq = 0; kq < 4; ++kq) {
            const int kk = kq * 4;
            float4 w0 = *(float4*)&Ws[(kk + 0) * 128 + c4];
            float4 w1 = *(float4*)&Ws[(kk + 1) * 128 + c4];
            float4 w2 = *(float4*)&Ws[(kk + 2) * 128 + c4];
            float4 w3 = *(float4*)&Ws[(kk + 3) * 128 + c4];
            #pragma unroll
            for (int i = 0; i < 4; ++i) {
                float4 av = *(float4*)&As[(rb + i) * 132 + k0 + kk];
                acc[i][0] += av.x * w0.x + av.y * w1.x + av.z * w2.x + av.w * w3.x;
                acc[i][1] += av.x * w0.y + av.y * w1.y + av.z * w2.y + av.w * w3.y;
                acc[i][2] += av.x * w0.z + av.y * w1.z + av.z * w2.z + av.w * w3.z;
                acc[i][3] += av.x * w0.w + av.y * w1.w + av.z * w2.w + av.w * w3.w;
            }
        }
    }

    float4 bv = make_float4(0.f, 0.f, 0.f, 0.f);
    if (bias) bv = *(const float4*)&bias[c4];
    #pragma unroll
    for (int i = 0; i < 4; ++i) {
        int r = row0 + rb + i;
        if (r < n_rows) {
            float o[4];
            o[0] = acc[i][0] + bv.x;
            o[1] = acc[i][1] + bv.y;
            o[2] = acc[i][2] + bv.z;
            o[3] = acc[i][3] + bv.w;
            if (do_swish) {
                #pragma unroll
                for (int c = 0; c < 4; ++c) o[c] = swish_f(o[c]);
            }
            if (out_bf) {
                #pragma unroll
                for (int c = 0; c < 4; ++c) {
                    int col = c4 + c;
                    int pos = ((col & 15) << 3) + (col >> 4);
                    out_bf[(size_t)r * FDIM + pos] = (__bf16)o[c];
                }
            } else {
                float4 ov = make_float4(o[0], o[1], o[2], o[3]);
                *(float4*)&out_f32[(size_t)r * FDIM + c4] = ov;
            }
        }
    }
}

// ---------------- dst-centric conv kernel (zero atomics) ----------------
// One wave per atom (grid-stride). Per atom: loop 16-edge tiles:
//   GEMM1: H = swish(fij_pad @ W1 + b1) -> hs (wave-local, no barrier)
//   GEMM2: Wfilt = H @ W2
//   epilogue: racc[n] += x[src]*(Wfilt+b2)*C   (registers)
// Then shfl_xor butterfly over kgrp bits and ONE plain store per col.

__global__ __launch_bounds__(256, 4) void conv_dst_kernel(
    const float* __restrict__ fij, const float* __restrict__ rij,
    const int* __restrict__ src,
    const int* __restrict__ perm, const int* __restrict__ rowstart,
    const int* __restrict__ count,
    const __bf16* __restrict__ w1p, const float* __restrict__ b1,
    const __bf16* __restrict__ w2p, const float* __restrict__ b2,
    const __bf16* __restrict__ xb, float* __restrict__ agg)
{
    __shared__ __bf16 hs[64 * 128];   // 16 KB: 4 waves x 16 rows x 256 B

    const int t = threadIdx.x;
    const int l = t & 63;
    const int w = t >> 6;             // 0..3
    const int lrow = l & 15;
    const int kgrp = l >> 4;
    const int row = (w << 4) | lrow;

    const int wid = blockIdx.x * 4 + w;
    const int nw = gridDim.x * 4;
    const f32x4 zero = {0.f, 0.f, 0.f, 0.f};

    // per-lane bias values (constant across atoms/tiles)
    float b1r[8], b2r[8];
    #pragma unroll
    for (int n = 0; n < 8; ++n) {
        b1r[n] = b1[(n << 4) + lrow];
        b2r[n] = b2[(n << 4) + lrow];
    }

    for (int d = wid; d < N_ATOMS; d += nw) {
        const int rs = rowstart[d];
        const int deg = count[d];

        float racc[8];
        #pragma unroll
        for (int n = 0; n < 8; ++n) racc[n] = 0.f;

        for (int t0 = 0; t0 < deg; t0 += 16) {
            // GEMM1 A-fragment: this lane supplies edge (t0+lrow), k = kgrp*8+j
            bf16x8 a;
            const int ea = t0 + lrow;
            if (ea < deg) {
                const float* fp = fij + (size_t)perm[rs + ea] * NB;
                #pragma unroll
                for (int j = 0; j < 8; ++j) {
                    int k = (kgrp << 3) + j;
                    a[j] = (k < NB) ? (__bf16)fp[k] : (__bf16)0.0f;
                }
            } else {
                #pragma unroll
                for (int j = 0; j < 8; ++j) a[j] = (__bf16)0.0f;
            }

            #pragma unroll
            for (int n = 0; n < 8; ++n) {
                bf16x8 b = *(const bf16x8*)(w1p + (((n << 6) + l) << 3));
                f32x4 h = __builtin_amdgcn_mfma_f32_16x16x32_bf16(a, b, zero, 0, 0, 0);
                #pragma unroll
                for (int r = 0; r < 4; ++r) {
                    int hrow = (w << 4) + (kgrp << 2) + r;   // wave-local C row
                    float hv = swish_f(h[r] + b1r[n]);
                    int byte = (hrow << 8) + (((n << 4) + lrow) << 1);
                    byte ^= SWZ(hrow);
                    *(__bf16*)((char*)hs + byte) = (__bf16)hv;
                }
            }
            // no barrier: hs rows for wave w produced & consumed by wave w only

            // GEMM2: Wfilt = H @ W2
            f32x4 acc[8];
            #pragma unroll
            for (int n = 0; n < 8; ++n) acc[n] = zero;

            #pragma unroll
            for (int ks = 0; ks < 4; ++ks) {
                int byte = (row << 8) + (ks << 6) + (kgrp << 4);
                byte ^= SWZ(row);
                bf16x8 a2 = *(const bf16x8*)((const char*)hs + byte);
                #pragma unroll
                for (int n = 0; n < 8; ++n) {
                    bf16x8 b = *(const bf16x8*)(w2p + ((((ks << 3) + n) << 6) + l) * 8);
                    acc[n] = __builtin_amdgcn_mfma_f32_16x16x32_bf16(a2, b, acc[n], 0, 0, 0);
                }
            }

            // Epilogue: this lane's C rows are edges t0 + kgrp*4 + r
            #pragma unroll
            for (int r = 0; r < 4; ++r) {
                int e = t0 + (kgrp << 2) + r;
                if (e < deg) {
                    int eid = perm[rs + e];
                    float rr = rij[eid];
                    float Cf = (rr < CUTOFF_F)
                             ? 0.5f * (__cosf(rr * PI_OVER_CUTOFF) + 1.0f) : 0.0f;
                    // permuted x row: cols {n*16+lrow} at [lrow*8 .. lrow*8+7]
                    bf16x8 xv = *(const bf16x8*)&xb[(size_t)src[eid] * FDIM + (lrow << 3)];
                    #pragma unroll
                    for (int n = 0; n < 8; ++n)
                        racc[n] += (float)xv[n] * (acc[n][r] + b2r[n]) * Cf;
                }
            }
        }

        // reduce over kgrp (lane bits 4,5); then 16 lanes store the row
        #pragma unroll
        for (int n = 0; n < 8; ++n) {
            racc[n] += __shfl_xor(racc[n], 16);
            racc[n] += __shfl_xor(racc[n], 32);
        }
        if (kgrp == 0) {
            #pragma unroll
            for (int n = 0; n < 8; ++n)
                agg[(size_t)d * FDIM + (n << 4) + lrow] = racc[n];
        }
    }
}

extern "C" void kernel_launch(void* const* d_in, const int* in_sizes, int n_in,
                              void* d_out, int out_size, void* d_ws, size_t ws_size,
                              hipStream_t stream)
{
    const float* feat   = (const float*)d_in[0];
    const float* fij    = (const float*)d_in[1];
    const float* rij    = (const float*)d_in[2];
    const int*   src    = (const int*)d_in[3];
    const int*   dst    = (const int*)d_in[4];
    const float* W_in2f = (const float*)d_in[5];
    const float* W_f1   = (const float*)d_in[6];
    const float* b_f1   = (const float*)d_in[7];
    const float* W_f2   = (const float*)d_in[8];
    const float* b_f2   = (const float*)d_in[9];
    const float* W_out  = (const float*)d_in[10];
    const float* b_out  = (const float*)d_in[11];
    float* out = (float*)d_out;

    // ws layout, total 19,840,960 B
    char* ws = (char*)d_ws;
    __bf16* xb       = (__bf16*)ws;                   // 12,800,000 B
    __bf16* w1p      = (__bf16*)(ws + 12800000);      //      8,192 B
    __bf16* w2p      = (__bf16*)(ws + 12808192);      //     32,768 B
    int*    cursor   = (int*)(ws + 12840960);         //    200,000 B
    int*    count    = (int*)(ws + 13040960);         //    200,000 B
    int*    rowstart = (int*)(ws + 13240960);         //    200,000 B
    int*    perm     = (int*)(ws + 13440960);         //  6,400,000 B
    float*  agg      = out;                           // every row stored once

    hipMemsetAsync(count, 0, N_ATOMS * sizeof(int), stream);

    hist_kernel<<<(N_EDGES + 255) / 256, 256, 0, stream>>>(dst, count);
    scan_simple_kernel<<<1, 256, 0, stream>>>(count, rowstart, cursor);
    scatter_kernel<<<(N_EDGES + 255) / 256, 256, 0, stream>>>(dst, cursor, perm);

    pack_b_kernel<<<(4096 + 255) / 256, 256, 0, stream>>>(W_f1, w1p, NB, 1);
    pack_b_kernel<<<(16384 + 255) / 256, 256, 0, stream>>>(W_f2, w2p, 128, 4);

    node_gemm_kernel<<<(N_ATOMS + 31) / 32, 256, 0, stream>>>(
        feat, W_in2f, nullptr, nullptr, xb, N_ATOMS, 0);

    conv_dst_kernel<<<2048, 256, 0, stream>>>(
        fij, rij, src, perm, rowstart, count, w1p, b_f1, w2p, b_f2, xb, agg);

    node_gemm_kernel<<<(N_ATOMS + 31) / 32, 256, 0, stream>>>(
        agg, W_out, b_out, out, nullptr, N_ATOMS, 1);
}

// Round 8
// 878.308 us; speedup vs baseline: 2.6773x; 2.6773x over previous
//
#include <hip/hip_runtime.h>
#include <hip/hip_bf16.h>
#include <math.h>

#define N_ATOMS 50000
#define N_EDGES 1600000
#define FDIM 128
#define NB 25
#define CUTOFF_F 5.0f
#define PI_OVER_CUTOFF 0.6283185307179586f

typedef __bf16 bf16x8 __attribute__((ext_vector_type(8)));
typedef float f32x4 __attribute__((ext_vector_type(4)));

__device__ __forceinline__ float swish_f(float v) {
    return v / (1.0f + __expf(-v));
}

// XOR swizzle on 16B slots.
#define SWZ(row) ((((row) & 7) ^ (((row) >> 3) & 1)) << 4)

// ---------------- weight packing ----------------
// Pack W [K_eff x 128] f32 into MFMA B-fragments (bf16), K zero-padded to KS*32.
// Fragment (ks,n): lane l, elem j holds W[ks*32 + (l>>4)*8 + j][n*16 + (l&15)].

__global__ void pack_b_kernel(const float* __restrict__ W, __bf16* __restrict__ out,
                              int K_eff, int KS)
{
    int idx = blockIdx.x * 256 + threadIdx.x;
    int total = KS * 8 * 64 * 8;
    if (idx >= total) return;
    int j  = idx & 7;
    int l  = (idx >> 3) & 63;
    int n  = (idx >> 9) & 7;
    int ks = idx >> 12;
    int k   = ks * 32 + ((l >> 4) << 3) + j;
    int col = (n << 4) + (l & 15);
    float v = (k < K_eff) ? W[k * FDIM + col] : 0.0f;
    out[idx] = (__bf16)v;
}

// ---------------- node GEMM (fp32 compute) ----------------
// If out_bf != null: write bf16 in PERMUTED layout pos=(col&15)*8+(col>>4).
// Else write f32 row-major to out_f32.

__global__ __launch_bounds__(256, 4) void node_gemm_kernel(
    const float* __restrict__ A, const float* __restrict__ W,
    const float* __restrict__ bias, float* __restrict__ out_f32,
    __bf16* __restrict__ out_bf, int n_rows, int do_swish)
{
    __shared__ float As[32 * 132];
    __shared__ float Ws[16 * 128];

    const int t = threadIdx.x;
    const int row0 = blockIdx.x * 32;
    const int c4 = (t & 31) * 4;
    const int rb = (t >> 5) * 4;

    for (int v = t; v < 1024; v += 256) {
        int r = v >> 5;
        int c = (v & 31) * 4;
        float4 val;
        if (row0 + r < n_rows) val = *(const float4*)&A[(size_t)(row0 + r) * FDIM + c];
        else val = make_float4(0.f, 0.f, 0.f, 0.f);
        *(float4*)&As[r * 132 + c] = val;
    }

    float acc[4][4];
    #pragma unroll
    for (int i = 0; i < 4; ++i)
        #pragma unroll
        for (int j = 0; j < 4; ++j) acc[i][j] = 0.f;

    for (int k0 = 0; k0 < 128; k0 += 16) {
        __syncthreads();
        for (int v = t; v < 512; v += 256)
            *(float4*)&Ws[v * 4] = *(const float4*)&W[k0 * 128 + v * 4];
        __syncthreads();
        #pragma unroll
        for (int kq = 0; kq < 4; ++kq) {
            const int kk = kq * 4;
            float4 w0 = *(float4*)&Ws[(kk + 0) * 128 + c4];
            float4 w1 = *(float4*)&Ws[(kk + 1) * 128 + c4];
            float4 w2 = *(float4*)&Ws[(kk + 2) * 128 + c4];
            float4 w3 = *(float4*)&Ws[(kk + 3) * 128 + c4];
            #pragma unroll
            for (int i = 0; i < 4; ++i) {
                float4 av = *(float4*)&As[(rb + i) * 132 + k0 + kk];
                acc[i][0] += av.x * w0.x + av.y * w1.x + av.z * w2.x + av.w * w3.x;
                acc[i][1] += av.x * w0.y + av.y * w1.y + av.z * w2.y + av.w * w3.y;
                acc[i][2] += av.x * w0.z + av.y * w1.z + av.z * w2.z + av.w * w3.z;
                acc[i][3] += av.x * w0.w + av.y * w1.w + av.z * w2.w + av.w * w3.w;
            }
        }
    }

    float4 bv = make_float4(0.f, 0.f, 0.f, 0.f);
    if (bias) bv = *(const float4*)&bias[c4];
    #pragma unroll
    for (int i = 0; i < 4; ++i) {
        int r = row0 + rb + i;
        if (r < n_rows) {
            float o[4];
            o[0] = acc[i][0] + bv.x;
            o[1] = acc[i][1] + bv.y;
            o[2] = acc[i][2] + bv.z;
            o[3] = acc[i][3] + bv.w;
            if (do_swish) {
                #pragma unroll
                for (int c = 0; c < 4; ++c) o[c] = swish_f(o[c]);
            }
            if (out_bf) {
                #pragma unroll
                for (int c = 0; c < 4; ++c) {
                    int col = c4 + c;
                    int pos = ((col & 15) << 3) + (col >> 4);
                    out_bf[(size_t)r * FDIM + pos] = (__bf16)o[c];
                }
            } else {
                float4 ov = make_float4(o[0], o[1], o[2], o[3]);
                *(float4*)&out_f32[(size_t)r * FDIM + c4] = ov;
            }
        }
    }
}

// ---------------- MFMA edge kernel (unsorted, weights in LDS) ----------------
// 64 edges/block, 4 waves, each wave owns a 16-edge strip.
// W1/W2 B-fragments staged in LDS once per block -> GEMM loops read b128 from
// LDS (conflict-free, ~low latency) instead of serialized global loads.

__global__ __launch_bounds__(256, 2) void edge_kernel(
    const float* __restrict__ fij, const float* __restrict__ rij,
    const int* __restrict__ src, const int* __restrict__ dst,
    const __bf16* __restrict__ w1p, const float* __restrict__ b1,
    const __bf16* __restrict__ w2p, const float* __restrict__ b2,
    const __bf16* __restrict__ xb, float* __restrict__ agg)
{
    __shared__ float  fs[64 * 32];    //  8 KB: fij tile, swizzled, K-padded
    __shared__ __bf16 hs[64 * 128];   // 16 KB: H tile, bf16, swizzled
    __shared__ __bf16 w1s[4096];      //  8 KB: W1 B-fragments
    __shared__ __bf16 w2s[16384];     // 32 KB: W2 B-fragments   (total 64 KB)

    const int t = threadIdx.x;
    const int l = t & 63;
    const int w = t >> 6;
    const int e0 = blockIdx.x * 64;
    const int lrow = l & 15;
    const int kgrp = l >> 4;
    const int row = (w << 4) | lrow;  // A-fragment row (edge within tile)

    // stage weight fragments (coalesced 16B copies)
    {
        const int4* g1 = (const int4*)w1p;
        int4* s1 = (int4*)w1s;
        for (int i = t; i < 512; i += 256) s1[i] = g1[i];
        const int4* g2 = (const int4*)w2p;
        int4* s2 = (int4*)w2s;
        for (int i = t; i < 2048; i += 256) s2[i] = g2[i];
    }

    // stage fij tile -> fs (contiguous edges; swizzled; K padded to 32)
    for (int idx = t; idx < 64 * 32; idx += 256) {
        int e = idx >> 5;
        int k = idx & 31;
        float v = (k < NB) ? fij[(size_t)(e0 + e) * NB + k] : 0.0f;
        int byte = (e << 7) + (k << 2);
        byte ^= SWZ(e);
        *(float*)((char*)fs + byte) = v;
    }
    __syncthreads();

    const f32x4 zero = {0.f, 0.f, 0.f, 0.f};

    // GEMM1: H = swish(fij_pad @ W1 + b1) -> hs (bf16, swizzled, wave-local)
    {
        int b0 = (row << 7) + (kgrp << 5);
        b0 ^= SWZ(row);
        float4 flo = *(const float4*)((const char*)fs + b0);
        float4 fhi = *(const float4*)((const char*)fs + (b0 ^ 16));
        bf16x8 a;
        a[0] = (__bf16)flo.x; a[1] = (__bf16)flo.y; a[2] = (__bf16)flo.z; a[3] = (__bf16)flo.w;
        a[4] = (__bf16)fhi.x; a[5] = (__bf16)fhi.y; a[6] = (__bf16)fhi.z; a[7] = (__bf16)fhi.w;

        #pragma unroll
        for (int n = 0; n < 8; ++n) {
            bf16x8 b = *(const bf16x8*)((const char*)w1s + (n << 10) + (l << 4));
            f32x4 h = __builtin_amdgcn_mfma_f32_16x16x32_bf16(a, b, zero, 0, 0, 0);
            float bb = b1[(n << 4) + lrow];
            #pragma unroll
            for (int r = 0; r < 4; ++r) {
                int hrow = (w << 4) + (kgrp << 2) + r;   // wave-local C row
                float hv = swish_f(h[r] + bb);
                int byte = (hrow << 8) + (((n << 4) + lrow) << 1);
                byte ^= SWZ(hrow);
                *(__bf16*)((char*)hs + byte) = (__bf16)hv;
            }
        }
    }
    // no barrier: hs rows for wave w are produced and consumed by wave w only

    // GEMM2: Wfilt = H @ W2; all 8 B-fragments per k-step live in registers
    f32x4 acc[8];
    #pragma unroll
    for (int n = 0; n < 8; ++n) acc[n] = zero;

    #pragma unroll
    for (int ks = 0; ks < 4; ++ks) {
        int byte = (row << 8) + (ks << 6) + (kgrp << 4);
        byte ^= SWZ(row);
        bf16x8 a2 = *(const bf16x8*)((const char*)hs + byte);
        bf16x8 bfr[8];
        #pragma unroll
        for (int n = 0; n < 8; ++n)
            bfr[n] = *(const bf16x8*)((const char*)w2s + (((ks << 3) + n) << 10) + (l << 4));
        #pragma unroll
        for (int n = 0; n < 8; ++n)
            acc[n] = __builtin_amdgcn_mfma_f32_16x16x32_bf16(a2, bfr[n], acc[n], 0, 0, 0);
    }

    // Epilogue: m = x[src]*(Wfilt+b2)*C -> direct global atomics (fire&forget)
    {
        const int els = (w << 4) + (kgrp << 2);   // this lane's 4 edges
        int de4[4];
        float Cf[4];
        bf16x8 xv4[4];
        #pragma unroll
        for (int r = 0; r < 4; ++r) {
            int e = e0 + els + r;
            float rr = rij[e];
            Cf[r] = (rr < CUTOFF_F) ? 0.5f * (__cosf(rr * PI_OVER_CUTOFF) + 1.0f) : 0.0f;
            de4[r] = dst[e];
            // permuted x row: cols {n*16+lrow, n=0..7} at [lrow*8 .. lrow*8+7]
            xv4[r] = *(const bf16x8*)&xb[(size_t)src[e] * FDIM + (lrow << 3)];
        }

        #pragma unroll
        for (int n = 0; n < 8; ++n) {
            int col = (n << 4) + lrow;
            float b2v = b2[col];
            #pragma unroll
            for (int r = 0; r < 4; ++r) {
                float m = (float)xv4[r][n] * (acc[n][r] + b2v) * Cf[r];
                unsafeAtomicAdd(&agg[(size_t)de4[r] * FDIM + col], m);
            }
        }
    }
}

extern "C" void kernel_launch(void* const* d_in, const int* in_sizes, int n_in,
                              void* d_out, int out_size, void* d_ws, size_t ws_size,
                              hipStream_t stream)
{
    const float* feat   = (const float*)d_in[0];
    const float* fij    = (const float*)d_in[1];
    const float* rij    = (const float*)d_in[2];
    const int*   src    = (const int*)d_in[3];
    const int*   dst    = (const int*)d_in[4];
    const float* W_in2f = (const float*)d_in[5];
    const float* W_f1   = (const float*)d_in[6];
    const float* b_f1   = (const float*)d_in[7];
    const float* W_f2   = (const float*)d_in[8];
    const float* b_f2   = (const float*)d_in[9];
    const float* W_out  = (const float*)d_in[10];
    const float* b_out  = (const float*)d_in[11];
    float* out = (float*)d_out;

    // ws layout, total 12,840,960 B
    char* ws = (char*)d_ws;
    __bf16* xb  = (__bf16*)ws;                 // 12,800,000 B
    __bf16* w1p = (__bf16*)(ws + 12800000);    //      8,192 B
    __bf16* w2p = (__bf16*)(ws + 12808192);    //     32,768 B
    float*  agg = out;                         // accumulate into d_out

    hipMemsetAsync(agg, 0, (size_t)N_ATOMS * FDIM * sizeof(float), stream);

    pack_b_kernel<<<(4096 + 255) / 256, 256, 0, stream>>>(W_f1, w1p, NB, 1);
    pack_b_kernel<<<(16384 + 255) / 256, 256, 0, stream>>>(W_f2, w2p, 128, 4);

    node_gemm_kernel<<<(N_ATOMS + 31) / 32, 256, 0, stream>>>(
        feat, W_in2f, nullptr, nullptr, xb, N_ATOMS, 0);

    edge_kernel<<<N_EDGES / 64, 256, 0, stream>>>(
        fij, rij, src, dst, w1p, b_f1, w2p, b_f2, xb, agg);

    node_gemm_kernel<<<(N_ATOMS + 31) / 32, 256, 0, stream>>>(
        agg, W_out, b_out, out, nullptr, N_ATOMS, 1);
}

// Round 9
// 871.906 us; speedup vs baseline: 2.6970x; 1.0073x over previous
//
#include <hip/hip_runtime.h>
#include <hip/hip_bf16.h>
#include <math.h>

#define N_ATOMS 50000
#define N_EDGES 1600000
#define FDIM 128
#define NB 25
#define CUTOFF_F 5.0f
#define PI_OVER_CUTOFF 0.6283185307179586f
#define NCH 196   // scan chunks of 256

typedef __bf16 bf16x8 __attribute__((ext_vector_type(8)));
typedef float f32x4 __attribute__((ext_vector_type(4)));

__device__ __forceinline__ float swish_f(float v) {
    return v / (1.0f + __expf(-v));
}

// XOR swizzle on 16B slots (for 256B-stride hs rows).
#define SWZ(row) ((((row) & 7) ^ (((row) >> 3) & 1)) << 4)

// ---------------- sort-by-dst machinery ----------------

__global__ void hist_kernel(const int* __restrict__ dst, int* __restrict__ count) {
    int i = blockIdx.x * 256 + threadIdx.x;
    if (i < N_EDGES) atomicAdd(&count[dst[i]], 1);
}

// Stage 1: per-chunk sums (196 blocks x 256 threads)
__global__ __launch_bounds__(256) void scan_chunk_kernel(
    const int* __restrict__ count, int* __restrict__ chunksum)
{
    __shared__ int red[256];
    const int t = threadIdx.x;
    const int i = blockIdx.x * 256 + t;
    red[t] = (i < N_ATOMS) ? count[i] : 0;
    __syncthreads();
    for (int o = 128; o > 0; o >>= 1) {
        if (t < o) red[t] += red[t + o];
        __syncthreads();
    }
    if (t == 0) chunksum[blockIdx.x] = red[0];
}

// Stage 2: serial exclusive scan of 196 chunk sums (trivial)
__global__ void scan_base_kernel(int* __restrict__ chunksum) {
    if (threadIdx.x == 0 && blockIdx.x == 0) {
        int run = 0;
        for (int i = 0; i < NCH; ++i) {
            int tmp = chunksum[i];
            chunksum[i] = run;
            run += tmp;
        }
    }
}

// Stage 3: per-chunk Hillis-Steele exclusive scan + chunk base -> cursor
__global__ __launch_bounds__(256) void scan_apply_kernel(
    const int* __restrict__ count, const int* __restrict__ chunksum,
    int* __restrict__ cursor)
{
    __shared__ int sa[256], sb[256];
    const int t = threadIdx.x;
    const int i = blockIdx.x * 256 + t;
    int v = (i < N_ATOMS) ? count[i] : 0;
    sa[t] = v;
    __syncthreads();
    int* cur = sa; int* nxt = sb;
    for (int o = 1; o < 256; o <<= 1) {
        int val = cur[t];
        if (t >= o) val += cur[t - o];
        nxt[t] = val;
        __syncthreads();
        int* tmp = cur; cur = nxt; nxt = tmp;
    }
    if (i < N_ATOMS) cursor[i] = chunksum[blockIdx.x] + cur[t] - v;  // exclusive
}

__global__ void scatter_kernel(const int* __restrict__ dst, int* __restrict__ cursor,
                               int* __restrict__ perm) {
    int i = blockIdx.x * 256 + threadIdx.x;
    if (i < N_EDGES) {
        int d = dst[i];
        int p = atomicAdd(&cursor[d], 1);
        perm[p] = i;
    }
}

// ---------------- weight packing ----------------
// Pack W [K_eff x 128] f32 into MFMA B-fragments (bf16), K zero-padded to KS*32.

__global__ void pack_b_kernel(const float* __restrict__ W, __bf16* __restrict__ out,
                              int K_eff, int KS)
{
    int idx = blockIdx.x * 256 + threadIdx.x;
    int total = KS * 8 * 64 * 8;
    if (idx >= total) return;
    int j  = idx & 7;
    int l  = (idx >> 3) & 63;
    int n  = (idx >> 9) & 7;
    int ks = idx >> 12;
    int k   = ks * 32 + ((l >> 4) << 3) + j;
    int col = (n << 4) + (l & 15);
    float v = (k < K_eff) ? W[k * FDIM + col] : 0.0f;
    out[idx] = (__bf16)v;
}

// ---------------- node GEMM (fp32 compute) ----------------
// If out_bf != null: write bf16 in PERMUTED layout pos=(col&15)*8+(col>>4).
// Else write f32 row-major to out_f32.

__global__ __launch_bounds__(256, 4) void node_gemm_kernel(
    const float* __restrict__ A, const float* __restrict__ W,
    const float* __restrict__ bias, float* __restrict__ out_f32,
    __bf16* __restrict__ out_bf, int n_rows, int do_swish)
{
    __shared__ float As[32 * 132];
    __shared__ float Ws[16 * 128];

    const int t = threadIdx.x;
    const int row0 = blockIdx.x * 32;
    const int c4 = (t & 31) * 4;
    const int rb = (t >> 5) * 4;

    for (int v = t; v < 1024; v += 256) {
        int r = v >> 5;
        int c = (v & 31) * 4;
        float4 val;
        if (row0 + r < n_rows) val = *(const float4*)&A[(size_t)(row0 + r) * FDIM + c];
        else val = make_float4(0.f, 0.f, 0.f, 0.f);
        *(float4*)&As[r * 132 + c] = val;
    }

    float acc[4][4];
    #pragma unroll
    for (int i = 0; i < 4; ++i)
        #pragma unroll
        for (int j = 0; j < 4; ++j) acc[i][j] = 0.f;

    for (int k0 = 0; k0 < 128; k0 += 16) {
        __syncthreads();
        for (int v = t; v < 512; v += 256)
            *(float4*)&Ws[v * 4] = *(const float4*)&W[k0 * 128 + v * 4];
        __syncthreads();
        #pragma unroll
        for (int kq = 0; kq < 4; ++kq) {
            const int kk = kq * 4;
            float4 w0 = *(float4*)&Ws[(kk + 0) * 128 + c4];
            float4 w1 = *(float4*)&Ws[(kk + 1) * 128 + c4];
            float4 w2 = *(float4*)&Ws[(kk + 2) * 128 + c4];
            float4 w3 = *(float4*)&Ws[(kk + 3) * 128 + c4];
            #pragma unroll
            for (int i = 0; i < 4; ++i) {
                float4 av = *(float4*)&As[(rb + i) * 132 + k0 + kk];
                acc[i][0] += av.x * w0.x + av.y * w1.x + av.z * w2.x + av.w * w3.x;
                acc[i][1] += av.x * w0.y + av.y * w1.y + av.z * w2.y + av.w * w3.y;
                acc[i][2] += av.x * w0.z + av.y * w1.z + av.z * w2.z + av.w * w3.z;
                acc[i][3] += av.x * w0.w + av.y * w1.w + av.z * w2.w + av.w * w3.w;
            }
        }
    }

    float4 bv = make_float4(0.f, 0.f, 0.f, 0.f);
    if (bias) bv = *(const float4*)&bias[c4];
    #pragma unroll
    for (int i = 0; i < 4; ++i) {
        int r = row0 + rb + i;
        if (r < n_rows) {
            float o[4];
            o[0] = acc[i][0] + bv.x;
            o[1] = acc[i][1] + bv.y;
            o[2] = acc[i][2] + bv.z;
            o[3] = acc[i][3] + bv.w;
            if (do_swish) {
                #pragma unroll
                for (int c = 0; c < 4; ++c) o[c] = swish_f(o[c]);
            }
            if (out_bf) {
                #pragma unroll
                for (int c = 0; c < 4; ++c) {
                    int col = c4 + c;
                    int pos = ((col & 15) << 3) + (col >> 4);
                    out_bf[(size_t)r * FDIM + pos] = (__bf16)o[c];
                }
            } else {
                float4 ov = make_float4(o[0], o[1], o[2], o[3]);
                *(float4*)&out_f32[(size_t)r * FDIM + c4] = ov;
            }
        }
    }
}

// ---------------- MFMA edge kernel over dst-sorted perm ----------------
// 64 edges/block, 4 waves. LDS 52KB -> 3 blocks/CU. W2 frags in LDS.
// Epilogue: wave-uniform-dst fast path (shfl reduce, 1 atomic/16 lanes),
// else r5-proven per-lane run compression.

__global__ __launch_bounds__(256, 3) void edge_kernel(
    const float* __restrict__ fij, const float* __restrict__ rij,
    const int* __restrict__ src, const int* __restrict__ dst,
    const int* __restrict__ perm,
    const __bf16* __restrict__ w1p, const float* __restrict__ b1,
    const __bf16* __restrict__ w2p, const float* __restrict__ b2,
    const __bf16* __restrict__ xb, float* __restrict__ agg)
{
    __shared__ __bf16 fs[64 * 32];    //  4 KB: fij tile, bf16, swizzled
    __shared__ __bf16 hs[64 * 128];   // 16 KB: H tile, bf16, swizzled
    __shared__ __bf16 w2s[16384];     // 32 KB: W2 B-fragments
    __shared__ int seS[64], deS[64];
    __shared__ float CeS[64];

    const int t = threadIdx.x;
    const int l = t & 63;
    const int w = t >> 6;
    const int e0 = blockIdx.x * 64;
    const int lrow = l & 15;
    const int kgrp = l >> 4;
    const int row = (w << 4) | lrow;  // A-fragment row (edge within tile)

    // stage W2 fragments (coalesced 16B copies)
    {
        const int4* g2 = (const int4*)w2p;
        int4* s2 = (int4*)w2s;
        for (int i = t; i < 2048; i += 256) s2[i] = g2[i];
    }

    // stage fij tile -> fs (bf16, swizzled). thread t: row e=t>>2, quarter kq=t&3
    {
        int e = t >> 2;
        int kq = t & 3;
        int eid = perm[e0 + e];
        const float* fp = fij + (size_t)eid * NB;
        bf16x8 tmp;
        #pragma unroll
        for (int j = 0; j < 8; ++j) {
            int k = (kq << 3) + j;
            tmp[j] = (k < NB) ? (__bf16)fp[k] : (__bf16)0.0f;
        }
        int byte = (e << 6) + (kq << 4);
        byte ^= ((e & 3) << 4);
        *(bf16x8*)((char*)fs + byte) = tmp;
    }

    // stage edge headers
    if (t < 64) {
        int eid = perm[e0 + t];
        seS[t] = src[eid];
        deS[t] = dst[eid];
        float rr = rij[eid];
        CeS[t] = (rr < CUTOFF_F) ? 0.5f * (__cosf(rr * PI_OVER_CUTOFF) + 1.0f) : 0.0f;
    }
    __syncthreads();

    const f32x4 zero = {0.f, 0.f, 0.f, 0.f};

    // GEMM1: H = swish(fij_pad @ W1 + b1) -> hs (bf16, swizzled, wave-local)
    {
        int b0 = (row << 6) + (kgrp << 4);
        b0 ^= ((row & 3) << 4);
        bf16x8 a = *(const bf16x8*)((const char*)fs + b0);

        #pragma unroll
        for (int n = 0; n < 8; ++n) {
            bf16x8 b = *(const bf16x8*)(w1p + (((n << 6) + l) << 3));
            f32x4 h = __builtin_amdgcn_mfma_f32_16x16x32_bf16(a, b, zero, 0, 0, 0);
            float bb = b1[(n << 4) + lrow];
            #pragma unroll
            for (int r = 0; r < 4; ++r) {
                int hrow = (w << 4) + (kgrp << 2) + r;   // wave-local C row
                float hv = swish_f(h[r] + bb);
                int byte = (hrow << 8) + (((n << 4) + lrow) << 1);
                byte ^= SWZ(hrow);
                *(__bf16*)((char*)hs + byte) = (__bf16)hv;
            }
        }
    }
    // no barrier: hs rows for wave w are produced and consumed by wave w only

    // GEMM2: Wfilt = H @ W2; 8 B-frags per k-step batched from LDS
    f32x4 acc[8];
    #pragma unroll
    for (int n = 0; n < 8; ++n) acc[n] = zero;

    #pragma unroll
    for (int ks = 0; ks < 4; ++ks) {
        int byte = (row << 8) + (ks << 6) + (kgrp << 4);
        byte ^= SWZ(row);
        bf16x8 a2 = *(const bf16x8*)((const char*)hs + byte);
        bf16x8 bfr[8];
        #pragma unroll
        for (int n = 0; n < 8; ++n)
            bfr[n] = *(const bf16x8*)((const char*)w2s + (((ks << 3) + n) << 10) + (l << 4));
        #pragma unroll
        for (int n = 0; n < 8; ++n)
            acc[n] = __builtin_amdgcn_mfma_f32_16x16x32_bf16(a2, bfr[n], acc[n], 0, 0, 0);
    }

    // Epilogue: m = x[src]*(Wfilt+b2)*C -> agg[dst]
    {
        const int els = (w << 4) + (kgrp << 2);   // this lane's 4 edges
        int se4[4], de4[4];
        float Cf[4];
        bf16x8 xv4[4];
        #pragma unroll
        for (int r = 0; r < 4; ++r) {
            se4[r] = seS[els + r];
            de4[r] = deS[els + r];
            Cf[r] = CeS[els + r];
            // permuted x row: cols {n*16+lrow, n=0..7} at [lrow*8 .. lrow*8+7]
            xv4[r] = *(const bf16x8*)&xb[(size_t)se4[r] * FDIM + (lrow << 3)];
        }

        const bool wave_uni = (deS[w << 4] == deS[(w << 4) + 15]);  // uniform branch
        if (wave_uni) {
            const size_t dbase = (size_t)deS[w << 4] * FDIM;
            #pragma unroll
            for (int n = 0; n < 8; ++n) {
                int col = (n << 4) + lrow;
                float b2v = b2[col];
                float s = 0.f;
                #pragma unroll
                for (int r = 0; r < 4; ++r)
                    s += (float)xv4[r][n] * (acc[n][r] + b2v) * Cf[r];
                s += __shfl_xor(s, 16);
                s += __shfl_xor(s, 32);
                if (kgrp == 0) unsafeAtomicAdd(&agg[dbase + col], s);
            }
        } else {
            const bool brk0 = (de4[0] != de4[1]);
            const bool brk1 = (de4[1] != de4[2]);
            const bool brk2 = (de4[2] != de4[3]);
            #pragma unroll
            for (int n = 0; n < 8; ++n) {
                int col = (n << 4) + lrow;
                float b2v = b2[col];
                float m[4];
                #pragma unroll
                for (int r = 0; r < 4; ++r)
                    m[r] = (float)xv4[r][n] * (acc[n][r] + b2v) * Cf[r];
                float run = m[0];
                if (brk0) { unsafeAtomicAdd(&agg[(size_t)de4[0] * FDIM + col], run); run = 0.f; }
                run += m[1];
                if (brk1) { unsafeAtomicAdd(&agg[(size_t)de4[1] * FDIM + col], run); run = 0.f; }
                run += m[2];
                if (brk2) { unsafeAtomicAdd(&agg[(size_t)de4[2] * FDIM + col], run); run = 0.f; }
                run += m[3];
                unsafeAtomicAdd(&agg[(size_t)de4[3] * FDIM + col], run);
            }
        }
    }
}

extern "C" void kernel_launch(void* const* d_in, const int* in_sizes, int n_in,
                              void* d_out, int out_size, void* d_ws, size_t ws_size,
                              hipStream_t stream)
{
    const float* feat   = (const float*)d_in[0];
    const float* fij    = (const float*)d_in[1];
    const float* rij    = (const float*)d_in[2];
    const int*   src    = (const int*)d_in[3];
    const int*   dst    = (const int*)d_in[4];
    const float* W_in2f = (const float*)d_in[5];
    const float* W_f1   = (const float*)d_in[6];
    const float* b_f1   = (const float*)d_in[7];
    const float* W_f2   = (const float*)d_in[8];
    const float* b_f2   = (const float*)d_in[9];
    const float* W_out  = (const float*)d_in[10];
    const float* b_out  = (const float*)d_in[11];
    float* out = (float*)d_out;

    // ws layout, total ~19.65 MB (r5-proven watermark)
    char* ws = (char*)d_ws;
    __bf16* xb       = (__bf16*)ws;                   // 12,800,000 B
    __bf16* w1p      = (__bf16*)(ws + 12800000);      //      8,192 B
    __bf16* w2p      = (__bf16*)(ws + 12808192);      //     32,768 B
    int*    cursor   = (int*)(ws + 12840960);         //    200,000 B
    int*    count    = (int*)(ws + 13040960);         //    200,000 B
    int*    chunksum = (int*)(ws + 13240960);         //      1,024 B
    int*    perm     = (int*)(ws + 13242112);         //  6,400,000 B
    float*  agg      = out;                           // accumulate into d_out

    hipMemsetAsync(agg, 0, (size_t)N_ATOMS * FDIM * sizeof(float), stream);
    hipMemsetAsync(count, 0, N_ATOMS * sizeof(int), stream);

    hist_kernel<<<(N_EDGES + 255) / 256, 256, 0, stream>>>(dst, count);
    scan_chunk_kernel<<<NCH, 256, 0, stream>>>(count, chunksum);
    scan_base_kernel<<<1, 64, 0, stream>>>(chunksum);
    scan_apply_kernel<<<NCH, 256, 0, stream>>>(count, chunksum, cursor);
    scatter_kernel<<<(N_EDGES + 255) / 256, 256, 0, stream>>>(dst, cursor, perm);

    pack_b_kernel<<<(4096 + 255) / 256, 256, 0, stream>>>(W_f1, w1p, NB, 1);
    pack_b_kernel<<<(16384 + 255) / 256, 256, 0, stream>>>(W_f2, w2p, 128, 4);

    node_gemm_kernel<<<(N_ATOMS + 31) / 32, 256, 0, stream>>>(
        feat, W_in2f, nullptr, nullptr, xb, N_ATOMS, 0);

    edge_kernel<<<N_EDGES / 64, 256, 0, stream>>>(
        fij, rij, src, dst, perm, w1p, b_f1, w2p, b_f2, xb, agg);

    node_gemm_kernel<<<(N_ATOMS + 31) / 32, 256, 0, stream>>>(
        agg, W_out, b_out, out, nullptr, N_ATOMS, 1);
}

// Round 10
// 741.998 us; speedup vs baseline: 3.1692x; 1.1751x over previous
//
#include <hip/hip_runtime.h>
#include <hip/hip_bf16.h>
#include <math.h>

#define N_ATOMS 50000
#define N_EDGES 1600000
#define FDIM 128
#define NB 25
#define CUTOFF_F 5.0f
#define PI_OVER_CUTOFF 0.6283185307179586f
#define NCH 196   // scan chunks of 256
#define NBLK 768  // persistent blocks for edge kernel

typedef __bf16 bf16x8 __attribute__((ext_vector_type(8)));
typedef float f32x4 __attribute__((ext_vector_type(4)));

__device__ __forceinline__ float swish_f(float v) {
    return v / (1.0f + __expf(-v));
}

// XOR swizzle on 16B slots (for 256B-stride hs rows).
#define SWZ(row) ((((row) & 7) ^ (((row) >> 3) & 1)) << 4)

// ---------------- sort-by-dst machinery (r9-proven) ----------------

__global__ void hist_kernel(const int* __restrict__ dst, int* __restrict__ count) {
    int i = blockIdx.x * 256 + threadIdx.x;
    if (i < N_EDGES) atomicAdd(&count[dst[i]], 1);
}

__global__ __launch_bounds__(256) void scan_chunk_kernel(
    const int* __restrict__ count, int* __restrict__ chunksum)
{
    __shared__ int red[256];
    const int t = threadIdx.x;
    const int i = blockIdx.x * 256 + t;
    red[t] = (i < N_ATOMS) ? count[i] : 0;
    __syncthreads();
    for (int o = 128; o > 0; o >>= 1) {
        if (t < o) red[t] += red[t + o];
        __syncthreads();
    }
    if (t == 0) chunksum[blockIdx.x] = red[0];
}

__global__ void scan_base_kernel(int* __restrict__ chunksum) {
    if (threadIdx.x == 0 && blockIdx.x == 0) {
        int run = 0;
        for (int i = 0; i < NCH; ++i) {
            int tmp = chunksum[i];
            chunksum[i] = run;
            run += tmp;
        }
    }
}

__global__ __launch_bounds__(256) void scan_apply_kernel(
    const int* __restrict__ count, const int* __restrict__ chunksum,
    int* __restrict__ cursor)
{
    __shared__ int sa[256], sb[256];
    const int t = threadIdx.x;
    const int i = blockIdx.x * 256 + t;
    int v = (i < N_ATOMS) ? count[i] : 0;
    sa[t] = v;
    __syncthreads();
    int* cur = sa; int* nxt = sb;
    for (int o = 1; o < 256; o <<= 1) {
        int val = cur[t];
        if (t >= o) val += cur[t - o];
        nxt[t] = val;
        __syncthreads();
        int* tmp = cur; cur = nxt; nxt = tmp;
    }
    if (i < N_ATOMS) cursor[i] = chunksum[blockIdx.x] + cur[t] - v;  // exclusive
}

__global__ void scatter_kernel(const int* __restrict__ dst, int* __restrict__ cursor,
                               int* __restrict__ perm) {
    int i = blockIdx.x * 256 + threadIdx.x;
    if (i < N_EDGES) {
        int d = dst[i];
        int p = atomicAdd(&cursor[d], 1);
        perm[p] = i;
    }
}

// ---------------- weight packing ----------------

__global__ void pack_b_kernel(const float* __restrict__ W, __bf16* __restrict__ out,
                              int K_eff, int KS)
{
    int idx = blockIdx.x * 256 + threadIdx.x;
    int total = KS * 8 * 64 * 8;
    if (idx >= total) return;
    int j  = idx & 7;
    int l  = (idx >> 3) & 63;
    int n  = (idx >> 9) & 7;
    int ks = idx >> 12;
    int k   = ks * 32 + ((l >> 4) << 3) + j;
    int col = (n << 4) + (l & 15);
    float v = (k < K_eff) ? W[k * FDIM + col] : 0.0f;
    out[idx] = (__bf16)v;
}

// ---------------- node GEMM (fp32 compute) ----------------

__global__ __launch_bounds__(256, 4) void node_gemm_kernel(
    const float* __restrict__ A, const float* __restrict__ W,
    const float* __restrict__ bias, float* __restrict__ out_f32,
    __bf16* __restrict__ out_bf, int n_rows, int do_swish)
{
    __shared__ float As[32 * 132];
    __shared__ float Ws[16 * 128];

    const int t = threadIdx.x;
    const int row0 = blockIdx.x * 32;
    const int c4 = (t & 31) * 4;
    const int rb = (t >> 5) * 4;

    for (int v = t; v < 1024; v += 256) {
        int r = v >> 5;
        int c = (v & 31) * 4;
        float4 val;
        if (row0 + r < n_rows) val = *(const float4*)&A[(size_t)(row0 + r) * FDIM + c];
        else val = make_float4(0.f, 0.f, 0.f, 0.f);
        *(float4*)&As[r * 132 + c] = val;
    }

    float acc[4][4];
    #pragma unroll
    for (int i = 0; i < 4; ++i)
        #pragma unroll
        for (int j = 0; j < 4; ++j) acc[i][j] = 0.f;

    for (int k0 = 0; k0 < 128; k0 += 16) {
        __syncthreads();
        for (int v = t; v < 512; v += 256)
            *(float4*)&Ws[v * 4] = *(const float4*)&W[k0 * 128 + v * 4];
        __syncthreads();
        #pragma unroll
        for (int kq = 0; kq < 4; ++kq) {
            const int kk = kq * 4;
            float4 w0 = *(float4*)&Ws[(kk + 0) * 128 + c4];
            float4 w1 = *(float4*)&Ws[(kk + 1) * 128 + c4];
            float4 w2 = *(float4*)&Ws[(kk + 2) * 128 + c4];
            float4 w3 = *(float4*)&Ws[(kk + 3) * 128 + c4];
            #pragma unroll
            for (int i = 0; i < 4; ++i) {
                float4 av = *(float4*)&As[(rb + i) * 132 + k0 + kk];
                acc[i][0] += av.x * w0.x + av.y * w1.x + av.z * w2.x + av.w * w3.x;
                acc[i][1] += av.x * w0.y + av.y * w1.y + av.z * w2.y + av.w * w3.y;
                acc[i][2] += av.x * w0.z + av.y * w1.z + av.z * w2.z + av.w * w3.z;
                acc[i][3] += av.x * w0.w + av.y * w1.w + av.z * w2.w + av.w * w3.w;
            }
        }
    }

    float4 bv = make_float4(0.f, 0.f, 0.f, 0.f);
    if (bias) bv = *(const float4*)&bias[c4];
    #pragma unroll
    for (int i = 0; i < 4; ++i) {
        int r = row0 + rb + i;
        if (r < n_rows) {
            float o[4];
            o[0] = acc[i][0] + bv.x;
            o[1] = acc[i][1] + bv.y;
            o[2] = acc[i][2] + bv.z;
            o[3] = acc[i][3] + bv.w;
            if (do_swish) {
                #pragma unroll
                for (int c = 0; c < 4; ++c) o[c] = swish_f(o[c]);
            }
            if (out_bf) {
                #pragma unroll
                for (int c = 0; c < 4; ++c) {
                    int col = c4 + c;
                    int pos = ((col & 15) << 3) + (col >> 4);
                    out_bf[(size_t)r * FDIM + pos] = (__bf16)o[c];
                }
            } else {
                float4 ov = make_float4(o[0], o[1], o[2], o[3]);
                *(float4*)&out_f32[(size_t)r * FDIM + c4] = ov;
            }
        }
    }
}

// ---------------- persistent-wave MFMA edge kernel ----------------
// 768 blocks x 4 waves; each wave independently processes 16-edge sorted
// tiles with software prefetch. No barriers in the main loop (hs wave-local,
// w2s read-only). W1 frags + biases in registers; W2 frags in LDS.

struct TileReg {
    float4 f0, f1;       // this lane's fij A-fragment data
    int   se[4], de[4];  // src/dst of lane's 4 epilogue edges
    float Cf[4];         // cutoff factors
};

__global__ __launch_bounds__(256, 3) void edge_kernel(
    const float* __restrict__ fij, const float* __restrict__ rij,
    const int* __restrict__ src, const int* __restrict__ dst,
    const int* __restrict__ perm,
    const __bf16* __restrict__ w1p, const float* __restrict__ b1,
    const __bf16* __restrict__ w2p, const float* __restrict__ b2,
    const __bf16* __restrict__ xb, float* __restrict__ agg)
{
    __shared__ __bf16 w2s[16384];       // 32 KB: W2 B-fragments
    __shared__ __bf16 hs[4][16 * 128];  // 16 KB: per-wave H tiles

    const int t = threadIdx.x;
    const int l = t & 63;
    const int w = t >> 6;
    const int lrow = l & 15;
    const int kgrp = l >> 4;

    // stage W2 fragments once per block
    {
        const int4* g2 = (const int4*)w2p;
        int4* s2 = (int4*)w2s;
        for (int i = t; i < 2048; i += 256) s2[i] = g2[i];
    }

    // W1 fragments + biases in registers (persistent)
    bf16x8 w1f[8];
    float b1r[8], b2r[8];
    #pragma unroll
    for (int n = 0; n < 8; ++n) {
        w1f[n] = *(const bf16x8*)(w1p + (((n << 6) + l) << 3));
        b1r[n] = b1[(n << 4) + lrow];
        b2r[n] = b2[(n << 4) + lrow];
    }
    __syncthreads();   // w2s ready; last barrier in the kernel

    __bf16* hw = hs[w];
    const f32x4 zero = {0.f, 0.f, 0.f, 0.f};

    const int gw = blockIdx.x * 4 + w;   // global wave id
    const int NW = NBLK * 4;
    const int NT = N_EDGES / 16;

    #define LOAD_TILE(T, base) do { \
        int ea_ = perm[(base) + lrow]; \
        const float* fp_ = fij + (size_t)ea_ * NB; \
        if (kgrp < 3) { \
            T.f0 = *(const float4*)(fp_ + (kgrp << 3)); \
            T.f1 = *(const float4*)(fp_ + (kgrp << 3) + 4); \
        } else { \
            T.f0 = make_float4(fp_[24], 0.f, 0.f, 0.f); \
            T.f1 = make_float4(0.f, 0.f, 0.f, 0.f); \
        } \
        _Pragma("unroll") \
        for (int r_ = 0; r_ < 4; ++r_) { \
            int pe_ = perm[(base) + (kgrp << 2) + r_]; \
            T.se[r_] = src[pe_]; \
            T.de[r_] = dst[pe_]; \
            float rr_ = rij[pe_]; \
            T.Cf[r_] = (rr_ < CUTOFF_F) \
                     ? 0.5f * (__cosf(rr_ * PI_OVER_CUTOFF) + 1.0f) : 0.0f; \
        } \
    } while (0)

    TileReg cur, nxt;
    int tb = gw;
    if (tb < NT) LOAD_TILE(cur, tb * 16);

    for (; tb < NT; tb += NW) {
        const int tn = tb + NW;
        if (tn < NT) LOAD_TILE(nxt, tn * 16);   // issue next tile's loads early

        // ---- A fragment from registers ----
        bf16x8 a;
        a[0] = (__bf16)cur.f0.x; a[1] = (__bf16)cur.f0.y;
        a[2] = (__bf16)cur.f0.z; a[3] = (__bf16)cur.f0.w;
        a[4] = (__bf16)cur.f1.x; a[5] = (__bf16)cur.f1.y;
        a[6] = (__bf16)cur.f1.z; a[7] = (__bf16)cur.f1.w;

        // ---- GEMM1: H = swish(fij_pad @ W1 + b1) -> hw (wave-local) ----
        #pragma unroll
        for (int n = 0; n < 8; ++n) {
            f32x4 h = __builtin_amdgcn_mfma_f32_16x16x32_bf16(a, w1f[n], zero, 0, 0, 0);
            #pragma unroll
            for (int r = 0; r < 4; ++r) {
                int hrow = (kgrp << 2) + r;           // 0..15
                float hv = swish_f(h[r] + b1r[n]);
                int byte = (hrow << 8) + (((n << 4) + lrow) << 1);
                byte ^= SWZ(hrow);
                *(__bf16*)((char*)hw + byte) = (__bf16)hv;
            }
        }

        // ---- GEMM2: Wfilt = H @ W2 (B-frags batched from LDS) ----
        f32x4 acc[8];
        #pragma unroll
        for (int n = 0; n < 8; ++n) acc[n] = zero;

        #pragma unroll
        for (int ks = 0; ks < 4; ++ks) {
            int byte = (lrow << 8) + (ks << 6) + (kgrp << 4);
            byte ^= SWZ(lrow);
            bf16x8 a2 = *(const bf16x8*)((const char*)hw + byte);
            bf16x8 bfr[8];
            #pragma unroll
            for (int n = 0; n < 8; ++n)
                bfr[n] = *(const bf16x8*)((const char*)w2s + (((ks << 3) + n) << 10) + (l << 4));
            #pragma unroll
            for (int n = 0; n < 8; ++n)
                acc[n] = __builtin_amdgcn_mfma_f32_16x16x32_bf16(a2, bfr[n], acc[n], 0, 0, 0);
        }

        // ---- Epilogue ----
        bf16x8 xv4[4];
        #pragma unroll
        for (int r = 0; r < 4; ++r)
            xv4[r] = *(const bf16x8*)&xb[(size_t)cur.se[r] * FDIM + (lrow << 3)];

        int d0 = __shfl(cur.de[0], 0);
        bool uni = __all(cur.de[0] == d0 && cur.de[3] == d0);

        if (uni) {
            const size_t dbase = (size_t)d0 * FDIM;
            #pragma unroll
            for (int n = 0; n < 8; ++n) {
                float s = 0.f;
                #pragma unroll
                for (int r = 0; r < 4; ++r)
                    s += (float)xv4[r][n] * (acc[n][r] + b2r[n]) * cur.Cf[r];
                s += __shfl_xor(s, 16);
                s += __shfl_xor(s, 32);
                if (kgrp == 0) unsafeAtomicAdd(&agg[dbase + (n << 4) + lrow], s);
            }
        } else {
            const bool brk0 = (cur.de[0] != cur.de[1]);
            const bool brk1 = (cur.de[1] != cur.de[2]);
            const bool brk2 = (cur.de[2] != cur.de[3]);
            #pragma unroll
            for (int n = 0; n < 8; ++n) {
                int col = (n << 4) + lrow;
                float m[4];
                #pragma unroll
                for (int r = 0; r < 4; ++r)
                    m[r] = (float)xv4[r][n] * (acc[n][r] + b2r[n]) * cur.Cf[r];
                float run = m[0];
                if (brk0) { unsafeAtomicAdd(&agg[(size_t)cur.de[0] * FDIM + col], run); run = 0.f; }
                run += m[1];
                if (brk1) { unsafeAtomicAdd(&agg[(size_t)cur.de[1] * FDIM + col], run); run = 0.f; }
                run += m[2];
                if (brk2) { unsafeAtomicAdd(&agg[(size_t)cur.de[2] * FDIM + col], run); run = 0.f; }
                run += m[3];
                unsafeAtomicAdd(&agg[(size_t)cur.de[3] * FDIM + col], run);
            }
        }

        cur = nxt;
    }
    #undef LOAD_TILE
}

extern "C" void kernel_launch(void* const* d_in, const int* in_sizes, int n_in,
                              void* d_out, int out_size, void* d_ws, size_t ws_size,
                              hipStream_t stream)
{
    const float* feat   = (const float*)d_in[0];
    const float* fij    = (const float*)d_in[1];
    const float* rij    = (const float*)d_in[2];
    const int*   src    = (const int*)d_in[3];
    const int*   dst    = (const int*)d_in[4];
    const float* W_in2f = (const float*)d_in[5];
    const float* W_f1   = (const float*)d_in[6];
    const float* b_f1   = (const float*)d_in[7];
    const float* W_f2   = (const float*)d_in[8];
    const float* b_f2   = (const float*)d_in[9];
    const float* W_out  = (const float*)d_in[10];
    const float* b_out  = (const float*)d_in[11];
    float* out = (float*)d_out;

    // ws layout, total ~19.65 MB
    char* ws = (char*)d_ws;
    __bf16* xb       = (__bf16*)ws;                   // 12,800,000 B
    __bf16* w1p      = (__bf16*)(ws + 12800000);      //      8,192 B
    __bf16* w2p      = (__bf16*)(ws + 12808192);      //     32,768 B
    int*    cursor   = (int*)(ws + 12840960);         //    200,000 B
    int*    count    = (int*)(ws + 13040960);         //    200,000 B
    int*    chunksum = (int*)(ws + 13240960);         //      1,024 B
    int*    perm     = (int*)(ws + 13242112);         //  6,400,000 B
    float*  agg      = out;                           // accumulate into d_out

    hipMemsetAsync(agg, 0, (size_t)N_ATOMS * FDIM * sizeof(float), stream);
    hipMemsetAsync(count, 0, N_ATOMS * sizeof(int), stream);

    hist_kernel<<<(N_EDGES + 255) / 256, 256, 0, stream>>>(dst, count);
    scan_chunk_kernel<<<NCH, 256, 0, stream>>>(count, chunksum);
    scan_base_kernel<<<1, 64, 0, stream>>>(chunksum);
    scan_apply_kernel<<<NCH, 256, 0, stream>>>(count, chunksum, cursor);
    scatter_kernel<<<(N_EDGES + 255) / 256, 256, 0, stream>>>(dst, cursor, perm);

    pack_b_kernel<<<(4096 + 255) / 256, 256, 0, stream>>>(W_f1, w1p, NB, 1);
    pack_b_kernel<<<(16384 + 255) / 256, 256, 0, stream>>>(W_f2, w2p, 128, 4);

    node_gemm_kernel<<<(N_ATOMS + 31) / 32, 256, 0, stream>>>(
        feat, W_in2f, nullptr, nullptr, xb, N_ATOMS, 0);

    edge_kernel<<<NBLK, 256, 0, stream>>>(
        fij, rij, src, dst, perm, w1p, b_f1, w2p, b_f2, xb, agg);

    node_gemm_kernel<<<(N_ATOMS + 31) / 32, 256, 0, stream>>>(
        agg, W_out, b_out, out, nullptr, N_ATOMS, 1);
}

// Round 11
// 693.685 us; speedup vs baseline: 3.3899x; 1.0696x over previous
//
#include <hip/hip_runtime.h>
#include <hip/hip_bf16.h>
#include <math.h>

#define N_ATOMS 50000
#define N_EDGES 1600000
#define FDIM 128
#define NB 25
#define CUTOFF_F 5.0f
#define PI_OVER_CUTOFF 0.6283185307179586f
#define NCH 196   // scan chunks of 256
#define NBLK 768  // persistent blocks for edge kernel

typedef __bf16 bf16x8 __attribute__((ext_vector_type(8)));
typedef float f32x4 __attribute__((ext_vector_type(4)));

__device__ __forceinline__ float swish_f(float v) {
    return v / (1.0f + __expf(-v));
}

// XOR swizzle on 16B slots (for 256B-stride hs rows).
#define SWZ(row) ((((row) & 7) ^ (((row) >> 3) & 1)) << 4)

// ---------------- sort-by-dst machinery ----------------

__global__ void hist_kernel(const int* __restrict__ dst, int* __restrict__ count) {
    int i = blockIdx.x * 256 + threadIdx.x;
    if (i < N_EDGES) atomicAdd(&count[dst[i]], 1);
}

__global__ __launch_bounds__(256) void scan_chunk_kernel(
    const int* __restrict__ count, int* __restrict__ chunksum)
{
    __shared__ int red[256];
    const int t = threadIdx.x;
    const int i = blockIdx.x * 256 + t;
    red[t] = (i < N_ATOMS) ? count[i] : 0;
    __syncthreads();
    for (int o = 128; o > 0; o >>= 1) {
        if (t < o) red[t] += red[t + o];
        __syncthreads();
    }
    if (t == 0) chunksum[blockIdx.x] = red[0];
}

// one block, 256 threads: exclusive Hillis-Steele scan of 196 chunk sums
__global__ __launch_bounds__(256) void scan_base_kernel(int* __restrict__ chunksum) {
    __shared__ int sa[256], sb[256];
    const int t = threadIdx.x;
    int v = (t < NCH) ? chunksum[t] : 0;
    sa[t] = v;
    __syncthreads();
    int* cur = sa; int* nxt = sb;
    for (int o = 1; o < 256; o <<= 1) {
        int val = cur[t];
        if (t >= o) val += cur[t - o];
        nxt[t] = val;
        __syncthreads();
        int* tmp = cur; cur = nxt; nxt = tmp;
    }
    if (t < NCH) chunksum[t] = cur[t] - v;   // exclusive
}

__global__ __launch_bounds__(256) void scan_apply_kernel(
    const int* __restrict__ count, const int* __restrict__ chunksum,
    int* __restrict__ cursor)
{
    __shared__ int sa[256], sb[256];
    const int t = threadIdx.x;
    const int i = blockIdx.x * 256 + t;
    int v = (i < N_ATOMS) ? count[i] : 0;
    sa[t] = v;
    __syncthreads();
    int* cur = sa; int* nxt = sb;
    for (int o = 1; o < 256; o <<= 1) {
        int val = cur[t];
        if (t >= o) val += cur[t - o];
        nxt[t] = val;
        __syncthreads();
        int* tmp = cur; cur = nxt; nxt = tmp;
    }
    if (i < N_ATOMS) cursor[i] = chunksum[blockIdx.x] + cur[t] - v;  // exclusive
}

__global__ void scatter_kernel(const int* __restrict__ dst, int* __restrict__ cursor,
                               int* __restrict__ perm) {
    int i = blockIdx.x * 256 + threadIdx.x;
    if (i < N_EDGES) {
        int d = dst[i];
        int p = atomicAdd(&cursor[d], 1);
        perm[p] = i;
    }
}

// ---------------- weight packing ----------------

__global__ void pack_b_kernel(const float* __restrict__ W, __bf16* __restrict__ out,
                              int K_eff, int KS)
{
    int idx = blockIdx.x * 256 + threadIdx.x;
    int total = KS * 8 * 64 * 8;
    if (idx >= total) return;
    int j  = idx & 7;
    int l  = (idx >> 3) & 63;
    int n  = (idx >> 9) & 7;
    int ks = idx >> 12;
    int k   = ks * 32 + ((l >> 4) << 3) + j;
    int col = (n << 4) + (l & 15);
    float v = (k < K_eff) ? W[k * FDIM + col] : 0.0f;
    out[idx] = (__bf16)v;
}

// ---------------- node GEMM (fp32 compute) ----------------

__global__ __launch_bounds__(256, 4) void node_gemm_kernel(
    const float* __restrict__ A, const float* __restrict__ W,
    const float* __restrict__ bias, float* __restrict__ out_f32,
    __bf16* __restrict__ out_bf, int n_rows, int do_swish)
{
    __shared__ float As[32 * 132];
    __shared__ float Ws[16 * 128];

    const int t = threadIdx.x;
    const int row0 = blockIdx.x * 32;
    const int c4 = (t & 31) * 4;
    const int rb = (t >> 5) * 4;

    for (int v = t; v < 1024; v += 256) {
        int r = v >> 5;
        int c = (v & 31) * 4;
        float4 val;
        if (row0 + r < n_rows) val = *(const float4*)&A[(size_t)(row0 + r) * FDIM + c];
        else val = make_float4(0.f, 0.f, 0.f, 0.f);
        *(float4*)&As[r * 132 + c] = val;
    }

    float acc[4][4];
    #pragma unroll
    for (int i = 0; i < 4; ++i)
        #pragma unroll
        for (int j = 0; j < 4; ++j) acc[i][j] = 0.f;

    for (int k0 = 0; k0 < 128; k0 += 16) {
        __syncthreads();
        for (int v = t; v < 512; v += 256)
            *(float4*)&Ws[v * 4] = *(const float4*)&W[k0 * 128 + v * 4];
        __syncthreads();
        #pragma unroll
        for (int kq = 0; kq < 4; ++kq) {
            const int kk = kq * 4;
            float4 w0 = *(float4*)&Ws[(kk + 0) * 128 + c4];
            float4 w1 = *(float4*)&Ws[(kk + 1) * 128 + c4];
            float4 w2 = *(float4*)&Ws[(kk + 2) * 128 + c4];
            float4 w3 = *(float4*)&Ws[(kk + 3) * 128 + c4];
            #pragma unroll
            for (int i = 0; i < 4; ++i) {
                float4 av = *(float4*)&As[(rb + i) * 132 + k0 + kk];
                acc[i][0] += av.x * w0.x + av.y * w1.x + av.z * w2.x + av.w * w3.x;
                acc[i][1] += av.x * w0.y + av.y * w1.y + av.z * w2.y + av.w * w3.y;
                acc[i][2] += av.x * w0.z + av.y * w1.z + av.z * w2.z + av.w * w3.z;
                acc[i][3] += av.x * w0.w + av.y * w1.w + av.z * w2.w + av.w * w3.w;
            }
        }
    }

    float4 bv = make_float4(0.f, 0.f, 0.f, 0.f);
    if (bias) bv = *(const float4*)&bias[c4];
    #pragma unroll
    for (int i = 0; i < 4; ++i) {
        int r = row0 + rb + i;
        if (r < n_rows) {
            float o[4];
            o[0] = acc[i][0] + bv.x;
            o[1] = acc[i][1] + bv.y;
            o[2] = acc[i][2] + bv.z;
            o[3] = acc[i][3] + bv.w;
            if (do_swish) {
                #pragma unroll
                for (int c = 0; c < 4; ++c) o[c] = swish_f(o[c]);
            }
            if (out_bf) {
                #pragma unroll
                for (int c = 0; c < 4; ++c) {
                    int col = c4 + c;
                    int pos = ((col & 15) << 3) + (col >> 4);
                    out_bf[(size_t)r * FDIM + pos] = (__bf16)o[c];
                }
            } else {
                float4 ov = make_float4(o[0], o[1], o[2], o[3]);
                *(float4*)&out_f32[(size_t)r * FDIM + c4] = ov;
            }
        }
    }
}

// ---------------- persistent-wave MFMA edge kernel ----------------
// 768 blocks x 4 waves; per-wave independent 16-edge tiles over sorted perm.
// 2-deep perm pipeline: perm loaded 2 tiles ahead, gathers (fij + own-edge
// header) issued 1 tile ahead, xv issued before GEMMs. Headers deduped via
// shfl (each lane loads only its own edge's src/dst/rij).

struct TileReg {
    float4 f0, f1;       // this lane's fij A-fragment data
    int   se_own, de_own;
    float rij_own;
};

__global__ __launch_bounds__(256, 3) void edge_kernel(
    const float* __restrict__ fij, const float* __restrict__ rij,
    const int* __restrict__ src, const int* __restrict__ dst,
    const int* __restrict__ perm,
    const __bf16* __restrict__ w1p, const float* __restrict__ b1,
    const __bf16* __restrict__ w2p, const float* __restrict__ b2,
    const __bf16* __restrict__ xb, float* __restrict__ agg)
{
    __shared__ __bf16 w2s[16384];       // 32 KB: W2 B-fragments
    __shared__ __bf16 hs[4][16 * 128];  // 16 KB: per-wave H tiles

    const int t = threadIdx.x;
    const int l = t & 63;
    const int w = t >> 6;
    const int lrow = l & 15;
    const int kgrp = l >> 4;

    // stage W2 fragments once per block
    {
        const int4* g2 = (const int4*)w2p;
        int4* s2 = (int4*)w2s;
        for (int i = t; i < 2048; i += 256) s2[i] = g2[i];
    }

    // W1 fragments + biases in registers (persistent)
    bf16x8 w1f[8];
    float b1r[8], b2r[8];
    #pragma unroll
    for (int n = 0; n < 8; ++n) {
        w1f[n] = *(const bf16x8*)(w1p + (((n << 6) + l) << 3));
        b1r[n] = b1[(n << 4) + lrow];
        b2r[n] = b2[(n << 4) + lrow];
    }
    __syncthreads();   // w2s ready; last barrier in the kernel

    __bf16* hw = hs[w];
    const f32x4 zero = {0.f, 0.f, 0.f, 0.f};

    const int gw = blockIdx.x * 4 + w;   // global wave id
    const int NW = NBLK * 4;
    const int NT = N_EDGES / 16;

    // gather for tile with this lane's own edge = base + lrow (= pv's index)
    #define GATHER(T, pv) do { \
        const float* fp_ = fij + (size_t)(pv) * NB; \
        if (kgrp < 3) { \
            T.f0 = *(const float4*)(fp_ + (kgrp << 3)); \
            T.f1 = *(const float4*)(fp_ + (kgrp << 3) + 4); \
        } else { \
            T.f0 = make_float4(fp_[24], 0.f, 0.f, 0.f); \
            T.f1 = make_float4(0.f, 0.f, 0.f, 0.f); \
        } \
        T.se_own = src[pv]; \
        T.de_own = dst[pv]; \
        T.rij_own = rij[pv]; \
    } while (0)

    TileReg cur, nxt;
    int pvB = 0;
    const int t0 = gw;
    if (t0 < NT) {
        int pvA = perm[(t0 << 4) + lrow];
        GATHER(cur, pvA);
    }
    if (t0 + NW < NT) pvB = perm[((t0 + NW) << 4) + lrow];

    for (int tb = t0; tb < NT; tb += NW) {
        const int tn = tb + NW;
        // issue next tile's gathers (perm value is a full iteration old)
        if (tn < NT) GATHER(nxt, pvB);
        // issue perm load 2 tiles ahead
        int pvC = 0;
        if (tn + NW < NT) pvC = perm[((tn + NW) << 4) + lrow];

        // ---- epilogue prep: shfl src ids (iteration-old), issue xv loads ----
        int se4[4];
        #pragma unroll
        for (int r = 0; r < 4; ++r) se4[r] = __shfl(cur.se_own, (kgrp << 2) + r);
        bf16x8 xv4[4];
        #pragma unroll
        for (int r = 0; r < 4; ++r)
            xv4[r] = *(const bf16x8*)&xb[(size_t)se4[r] * FDIM + (lrow << 3)];

        // ---- A fragment from registers ----
        bf16x8 a;
        a[0] = (__bf16)cur.f0.x; a[1] = (__bf16)cur.f0.y;
        a[2] = (__bf16)cur.f0.z; a[3] = (__bf16)cur.f0.w;
        a[4] = (__bf16)cur.f1.x; a[5] = (__bf16)cur.f1.y;
        a[6] = (__bf16)cur.f1.z; a[7] = (__bf16)cur.f1.w;

        // ---- GEMM1: H = swish(fij_pad @ W1 + b1) -> hw (wave-local) ----
        #pragma unroll
        for (int n = 0; n < 8; ++n) {
            f32x4 h = __builtin_amdgcn_mfma_f32_16x16x32_bf16(a, w1f[n], zero, 0, 0, 0);
            #pragma unroll
            for (int r = 0; r < 4; ++r) {
                int hrow = (kgrp << 2) + r;           // 0..15
                float hv = swish_f(h[r] + b1r[n]);
                int byte = (hrow << 8) + (((n << 4) + lrow) << 1);
                byte ^= SWZ(hrow);
                *(__bf16*)((char*)hw + byte) = (__bf16)hv;
            }
        }
        // no barrier: hw is wave-local

        // ---- GEMM2: Wfilt = H @ W2 (B-frags batched from LDS) ----
        f32x4 acc[8];
        #pragma unroll
        for (int n = 0; n < 8; ++n) acc[n] = zero;

        #pragma unroll
        for (int ks = 0; ks < 4; ++ks) {
            int byte = (lrow << 8) + (ks << 6) + (kgrp << 4);
            byte ^= SWZ(lrow);
            bf16x8 a2 = *(const bf16x8*)((const char*)hw + byte);
            bf16x8 bfr[8];
            #pragma unroll
            for (int n = 0; n < 8; ++n)
                bfr[n] = *(const bf16x8*)((const char*)w2s + (((ks << 3) + n) << 10) + (l << 4));
            #pragma unroll
            for (int n = 0; n < 8; ++n)
                acc[n] = __builtin_amdgcn_mfma_f32_16x16x32_bf16(a2, bfr[n], acc[n], 0, 0, 0);
        }

        // ---- Epilogue: cutoff + dst via shfl, run-compressed atomics ----
        float Cf_own = (cur.rij_own < CUTOFF_F)
                     ? 0.5f * (__cosf(cur.rij_own * PI_OVER_CUTOFF) + 1.0f) : 0.0f;
        float Cf[4]; int de4[4];
        #pragma unroll
        for (int r = 0; r < 4; ++r) {
            Cf[r]  = __shfl(Cf_own, (kgrp << 2) + r);
            de4[r] = __shfl(cur.de_own, (kgrp << 2) + r);
        }

        int d0 = __shfl(cur.de_own, 0);
        bool uni = __all(cur.de_own == d0);

        if (uni) {
            const size_t dbase = (size_t)d0 * FDIM;
            #pragma unroll
            for (int n = 0; n < 8; ++n) {
                float s = 0.f;
                #pragma unroll
                for (int r = 0; r < 4; ++r)
                    s += (float)xv4[r][n] * (acc[n][r] + b2r[n]) * Cf[r];
                s += __shfl_xor(s, 16);
                s += __shfl_xor(s, 32);
                if (kgrp == 0) unsafeAtomicAdd(&agg[dbase + (n << 4) + lrow], s);
            }
        } else {
            const bool brk0 = (de4[0] != de4[1]);
            const bool brk1 = (de4[1] != de4[2]);
            const bool brk2 = (de4[2] != de4[3]);
            #pragma unroll
            for (int n = 0; n < 8; ++n) {
                int col = (n << 4) + lrow;
                float m[4];
                #pragma unroll
                for (int r = 0; r < 4; ++r)
                    m[r] = (float)xv4[r][n] * (acc[n][r] + b2r[n]) * Cf[r];
                float run = m[0];
                if (brk0) { unsafeAtomicAdd(&agg[(size_t)de4[0] * FDIM + col], run); run = 0.f; }
                run += m[1];
                if (brk1) { unsafeAtomicAdd(&agg[(size_t)de4[1] * FDIM + col], run); run = 0.f; }
                run += m[2];
                if (brk2) { unsafeAtomicAdd(&agg[(size_t)de4[2] * FDIM + col], run); run = 0.f; }
                run += m[3];
                unsafeAtomicAdd(&agg[(size_t)de4[3] * FDIM + col], run);
            }
        }

        pvB = pvC;
        cur = nxt;
    }
    #undef GATHER
}

extern "C" void kernel_launch(void* const* d_in, const int* in_sizes, int n_in,
                              void* d_out, int out_size, void* d_ws, size_t ws_size,
                              hipStream_t stream)
{
    const float* feat   = (const float*)d_in[0];
    const float* fij    = (const float*)d_in[1];
    const float* rij    = (const float*)d_in[2];
    const int*   src    = (const int*)d_in[3];
    const int*   dst    = (const int*)d_in[4];
    const float* W_in2f = (const float*)d_in[5];
    const float* W_f1   = (const float*)d_in[6];
    const float* b_f1   = (const float*)d_in[7];
    const float* W_f2   = (const float*)d_in[8];
    const float* b_f2   = (const float*)d_in[9];
    const float* W_out  = (const float*)d_in[10];
    const float* b_out  = (const float*)d_in[11];
    float* out = (float*)d_out;

    // ws layout, total ~19.65 MB
    char* ws = (char*)d_ws;
    __bf16* xb       = (__bf16*)ws;                   // 12,800,000 B
    __bf16* w1p      = (__bf16*)(ws + 12800000);      //      8,192 B
    __bf16* w2p      = (__bf16*)(ws + 12808192);      //     32,768 B
    int*    cursor   = (int*)(ws + 12840960);         //    200,000 B
    int*    count    = (int*)(ws + 13040960);         //    200,000 B
    int*    chunksum = (int*)(ws + 13240960);         //      1,024 B
    int*    perm     = (int*)(ws + 13242112);         //  6,400,000 B
    float*  agg      = out;                           // accumulate into d_out

    hipMemsetAsync(agg, 0, (size_t)N_ATOMS * FDIM * sizeof(float), stream);
    hipMemsetAsync(count, 0, N_ATOMS * sizeof(int), stream);

    hist_kernel<<<(N_EDGES + 255) / 256, 256, 0, stream>>>(dst, count);
    scan_chunk_kernel<<<NCH, 256, 0, stream>>>(count, chunksum);
    scan_base_kernel<<<1, 256, 0, stream>>>(chunksum);
    scan_apply_kernel<<<NCH, 256, 0, stream>>>(count, chunksum, cursor);
    scatter_kernel<<<(N_EDGES + 255) / 256, 256, 0, stream>>>(dst, cursor, perm);

    pack_b_kernel<<<(4096 + 255) / 256, 256, 0, stream>>>(W_f1, w1p, NB, 1);
    pack_b_kernel<<<(16384 + 255) / 256, 256, 0, stream>>>(W_f2, w2p, 128, 4);

    node_gemm_kernel<<<(N_ATOMS + 31) / 32, 256, 0, stream>>>(
        feat, W_in2f, nullptr, nullptr, xb, N_ATOMS, 0);

    edge_kernel<<<NBLK, 256, 0, stream>>>(
        fij, rij, src, dst, perm, w1p, b_f1, w2p, b_f2, xb, agg);

    node_gemm_kernel<<<(N_ATOMS + 31) / 32, 256, 0, stream>>>(
        agg, W_out, b_out, out, nullptr, N_ATOMS, 1);
}

// Round 12
// 614.871 us; speedup vs baseline: 3.8244x; 1.1282x over previous
//
#include <hip/hip_runtime.h>
#include <hip/hip_bf16.h>
#include <math.h>

#define N_ATOMS 50000
#define N_EDGES 1600000
#define FDIM 128
#define NB 25
#define CUTOFF_F 5.0f
#define PI_OVER_CUTOFF 0.6283185307179586f
#define NCH 196   // scan chunks of 256
#define NBLK 512  // persistent blocks for edge kernel (2/CU x 256 CU)

typedef __bf16 bf16x8 __attribute__((ext_vector_type(8)));
typedef float f32x4 __attribute__((ext_vector_type(4)));

__device__ __forceinline__ float swish_f(float v) {
    return v / (1.0f + __expf(-v));
}

// XOR swizzle on 16B slots (for 256B-stride hs rows).
#define SWZ(row) ((((row) & 7) ^ (((row) >> 3) & 1)) << 4)

// ---------------- sort-by-dst machinery (r9/r11-proven) ----------------

__global__ void hist_kernel(const int* __restrict__ dst, int* __restrict__ count) {
    int i = blockIdx.x * 256 + threadIdx.x;
    if (i < N_EDGES) atomicAdd(&count[dst[i]], 1);
}

__global__ __launch_bounds__(256) void scan_chunk_kernel(
    const int* __restrict__ count, int* __restrict__ chunksum)
{
    __shared__ int red[256];
    const int t = threadIdx.x;
    const int i = blockIdx.x * 256 + t;
    red[t] = (i < N_ATOMS) ? count[i] : 0;
    __syncthreads();
    for (int o = 128; o > 0; o >>= 1) {
        if (t < o) red[t] += red[t + o];
        __syncthreads();
    }
    if (t == 0) chunksum[blockIdx.x] = red[0];
}

__global__ __launch_bounds__(256) void scan_base_kernel(int* __restrict__ chunksum) {
    __shared__ int sa[256], sb[256];
    const int t = threadIdx.x;
    int v = (t < NCH) ? chunksum[t] : 0;
    sa[t] = v;
    __syncthreads();
    int* cur = sa; int* nxt = sb;
    for (int o = 1; o < 256; o <<= 1) {
        int val = cur[t];
        if (t >= o) val += cur[t - o];
        nxt[t] = val;
        __syncthreads();
        int* tmp = cur; cur = nxt; nxt = tmp;
    }
    if (t < NCH) chunksum[t] = cur[t] - v;   // exclusive
}

__global__ __launch_bounds__(256) void scan_apply_kernel(
    const int* __restrict__ count, const int* __restrict__ chunksum,
    int* __restrict__ cursor)
{
    __shared__ int sa[256], sb[256];
    const int t = threadIdx.x;
    const int i = blockIdx.x * 256 + t;
    int v = (i < N_ATOMS) ? count[i] : 0;
    sa[t] = v;
    __syncthreads();
    int* cur = sa; int* nxt = sb;
    for (int o = 1; o < 256; o <<= 1) {
        int val = cur[t];
        if (t >= o) val += cur[t - o];
        nxt[t] = val;
        __syncthreads();
        int* tmp = cur; cur = nxt; nxt = tmp;
    }
    if (i < N_ATOMS) cursor[i] = chunksum[blockIdx.x] + cur[t] - v;  // exclusive
}

__global__ void scatter_kernel(const int* __restrict__ dst, int* __restrict__ cursor,
                               int* __restrict__ perm) {
    int i = blockIdx.x * 256 + threadIdx.x;
    if (i < N_EDGES) {
        int d = dst[i];
        int p = atomicAdd(&cursor[d], 1);
        perm[p] = i;
    }
}

// ---------------- weight packing ----------------

__global__ void pack_b_kernel(const float* __restrict__ W, __bf16* __restrict__ out,
                              int K_eff, int KS)
{
    int idx = blockIdx.x * 256 + threadIdx.x;
    int total = KS * 8 * 64 * 8;
    if (idx >= total) return;
    int j  = idx & 7;
    int l  = (idx >> 3) & 63;
    int n  = (idx >> 9) & 7;
    int ks = idx >> 12;
    int k   = ks * 32 + ((l >> 4) << 3) + j;
    int col = (n << 4) + (l & 15);
    float v = (k < K_eff) ? W[k * FDIM + col] : 0.0f;
    out[idx] = (__bf16)v;
}

// ---------------- MFMA node GEMM ----------------
// out = act(A @ W + bias); A:[50000,128] f32, W packed B-frags (K=128,KS=4).
// One wave per 16-row tile (50000 = 3125 x 16 exactly). B staged in LDS.
// If out_bf != null: write bf16 PERMUTED pos=(col&15)*8+(col>>4) (one 16B
// store per C-row). Else write f32 row-major (in-place safe per 16-row tile).

__global__ __launch_bounds__(512, 2) void node_mfma_kernel(
    const float* __restrict__ A, const __bf16* __restrict__ wp,
    const float* __restrict__ bias,
    __bf16* __restrict__ out_bf, float* __restrict__ out_f32,
    int do_swish)
{
    __shared__ __bf16 ws_[16384];   // 32 KB packed B

    const int t = threadIdx.x;
    const int l = t & 63;
    const int w = t >> 6;
    const int lrow = l & 15;
    const int kgrp = l >> 4;

    {
        const int4* g = (const int4*)wp;
        int4* s = (int4*)ws_;
        for (int i = t; i < 2048; i += 512) s[i] = g[i];
    }
    float br[8];
    #pragma unroll
    for (int n = 0; n < 8; ++n) br[n] = bias ? bias[(n << 4) + lrow] : 0.0f;
    __syncthreads();

    const int tile = blockIdx.x * 8 + w;
    if (tile >= N_ATOMS / 16) return;
    const int row0 = tile << 4;

    // A-fragments: lane supplies A[row0+lrow][ks*32 + kgrp*8 + j]
    bf16x8 af[4];
    const float* ap = A + (size_t)(row0 + lrow) * FDIM + (kgrp << 3);
    #pragma unroll
    for (int ks = 0; ks < 4; ++ks) {
        float4 lo = *(const float4*)(ap + (ks << 5));
        float4 hi = *(const float4*)(ap + (ks << 5) + 4);
        af[ks][0] = (__bf16)lo.x; af[ks][1] = (__bf16)lo.y;
        af[ks][2] = (__bf16)lo.z; af[ks][3] = (__bf16)lo.w;
        af[ks][4] = (__bf16)hi.x; af[ks][5] = (__bf16)hi.y;
        af[ks][6] = (__bf16)hi.z; af[ks][7] = (__bf16)hi.w;
    }

    const f32x4 zero = {0.f, 0.f, 0.f, 0.f};
    f32x4 acc[8];
    #pragma unroll
    for (int n = 0; n < 8; ++n) acc[n] = zero;

    #pragma unroll
    for (int ks = 0; ks < 4; ++ks) {
        bf16x8 bfr[8];
        #pragma unroll
        for (int n = 0; n < 8; ++n)
            bfr[n] = *(const bf16x8*)((const char*)ws_ + (((ks << 3) + n) << 10) + (l << 4));
        #pragma unroll
        for (int n = 0; n < 8; ++n)
            acc[n] = __builtin_amdgcn_mfma_f32_16x16x32_bf16(af[ks], bfr[n], acc[n], 0, 0, 0);
    }

    // C-layout: lane holds rows row0+4*kgrp+r, cols 16n+lrow
    if (out_bf) {
        #pragma unroll
        for (int r = 0; r < 4; ++r) {
            bf16x8 o;
            #pragma unroll
            for (int n = 0; n < 8; ++n) {
                float v = acc[n][r] + br[n];
                if (do_swish) v = swish_f(v);
                o[n] = (__bf16)v;
            }
            // permuted: cols 16n+lrow -> pos lrow*8+n (contiguous 16B)
            *(bf16x8*)&out_bf[(size_t)(row0 + (kgrp << 2) + r) * FDIM + (lrow << 3)] = o;
        }
    } else {
        #pragma unroll
        for (int r = 0; r < 4; ++r) {
            int orow = row0 + (kgrp << 2) + r;
            #pragma unroll
            for (int n = 0; n < 8; ++n) {
                float v = acc[n][r] + br[n];
                if (do_swish) v = swish_f(v);
                out_f32[(size_t)orow * FDIM + (n << 4) + lrow] = v;
            }
        }
    }
}

// ---------------- persistent-wave MFMA edge kernel ----------------
// 512 blocks x 8 waves (2 blocks/CU, 16 waves/CU); per-wave independent
// 16-edge tiles over sorted perm; 2-deep perm pipeline; headers deduped
// via shfl; run-compressed / wave-uniform atomics.

struct TileReg {
    float4 f0, f1;       // this lane's fij A-fragment data
    int   se_own, de_own;
    float rij_own;
};

__global__ __launch_bounds__(512, 2) void edge_kernel(
    const float* __restrict__ fij, const float* __restrict__ rij,
    const int* __restrict__ src, const int* __restrict__ dst,
    const int* __restrict__ perm,
    const __bf16* __restrict__ w1p, const float* __restrict__ b1,
    const __bf16* __restrict__ w2p, const float* __restrict__ b2,
    const __bf16* __restrict__ xb, float* __restrict__ agg)
{
    __shared__ __bf16 w2s[16384];       // 32 KB: W2 B-fragments
    __shared__ __bf16 hs[8][16 * 128];  // 32 KB: per-wave H tiles

    const int t = threadIdx.x;
    const int l = t & 63;
    const int w = t >> 6;               // 0..7
    const int lrow = l & 15;
    const int kgrp = l >> 4;

    // stage W2 fragments once per block
    {
        const int4* g2 = (const int4*)w2p;
        int4* s2 = (int4*)w2s;
        for (int i = t; i < 2048; i += 512) s2[i] = g2[i];
    }

    // W1 fragments + biases in registers (persistent)
    bf16x8 w1f[8];
    float b1r[8], b2r[8];
    #pragma unroll
    for (int n = 0; n < 8; ++n) {
        w1f[n] = *(const bf16x8*)(w1p + (((n << 6) + l) << 3));
        b1r[n] = b1[(n << 4) + lrow];
        b2r[n] = b2[(n << 4) + lrow];
    }
    __syncthreads();   // w2s ready; last barrier in the kernel

    __bf16* hw = hs[w];
    const f32x4 zero = {0.f, 0.f, 0.f, 0.f};

    const int gw = blockIdx.x * 8 + w;   // global wave id
    const int NW = NBLK * 8;
    const int NT = N_EDGES / 16;

    #define GATHER(T, pv) do { \
        const float* fp_ = fij + (size_t)(pv) * NB; \
        if (kgrp < 3) { \
            T.f0 = *(const float4*)(fp_ + (kgrp << 3)); \
            T.f1 = *(const float4*)(fp_ + (kgrp << 3) + 4); \
        } else { \
            T.f0 = make_float4(fp_[24], 0.f, 0.f, 0.f); \
            T.f1 = make_float4(0.f, 0.f, 0.f, 0.f); \
        } \
        T.se_own = src[pv]; \
        T.de_own = dst[pv]; \
        T.rij_own = rij[pv]; \
    } while (0)

    TileReg cur, nxt;
    int pvB = 0;
    const int t0 = gw;
    if (t0 < NT) {
        int pvA = perm[(t0 << 4) + lrow];
        GATHER(cur, pvA);
    }
    if (t0 + NW < NT) pvB = perm[((t0 + NW) << 4) + lrow];

    for (int tb = t0; tb < NT; tb += NW) {
        const int tn = tb + NW;
        if (tn < NT) GATHER(nxt, pvB);
        int pvC = 0;
        if (tn + NW < NT) pvC = perm[((tn + NW) << 4) + lrow];

        // ---- epilogue prep: shfl src ids, issue xv loads early ----
        int se4[4];
        #pragma unroll
        for (int r = 0; r < 4; ++r) se4[r] = __shfl(cur.se_own, (kgrp << 2) + r);
        bf16x8 xv4[4];
        #pragma unroll
        for (int r = 0; r < 4; ++r)
            xv4[r] = *(const bf16x8*)&xb[(size_t)se4[r] * FDIM + (lrow << 3)];

        // ---- A fragment from registers ----
        bf16x8 a;
        a[0] = (__bf16)cur.f0.x; a[1] = (__bf16)cur.f0.y;
        a[2] = (__bf16)cur.f0.z; a[3] = (__bf16)cur.f0.w;
        a[4] = (__bf16)cur.f1.x; a[5] = (__bf16)cur.f1.y;
        a[6] = (__bf16)cur.f1.z; a[7] = (__bf16)cur.f1.w;

        // ---- GEMM1: H = swish(fij_pad @ W1 + b1) -> hw (wave-local) ----
        #pragma unroll
        for (int n = 0; n < 8; ++n) {
            f32x4 h = __builtin_amdgcn_mfma_f32_16x16x32_bf16(a, w1f[n], zero, 0, 0, 0);
            #pragma unroll
            for (int r = 0; r < 4; ++r) {
                int hrow = (kgrp << 2) + r;           // 0..15
                float hv = swish_f(h[r] + b1r[n]);
                int byte = (hrow << 8) + (((n << 4) + lrow) << 1);
                byte ^= SWZ(hrow);
                *(__bf16*)((char*)hw + byte) = (__bf16)hv;
            }
        }
        // no barrier: hw is wave-local

        // ---- GEMM2: Wfilt = H @ W2 (B-frags batched from LDS) ----
        f32x4 acc[8];
        #pragma unroll
        for (int n = 0; n < 8; ++n) acc[n] = zero;

        #pragma unroll
        for (int ks = 0; ks < 4; ++ks) {
            int byte = (lrow << 8) + (ks << 6) + (kgrp << 4);
            byte ^= SWZ(lrow);
            bf16x8 a2 = *(const bf16x8*)((const char*)hw + byte);
            bf16x8 bfr[8];
            #pragma unroll
            for (int n = 0; n < 8; ++n)
                bfr[n] = *(const bf16x8*)((const char*)w2s + (((ks << 3) + n) << 10) + (l << 4));
            #pragma unroll
            for (int n = 0; n < 8; ++n)
                acc[n] = __builtin_amdgcn_mfma_f32_16x16x32_bf16(a2, bfr[n], acc[n], 0, 0, 0);
        }

        // ---- Epilogue: cutoff + dst via shfl, run-compressed atomics ----
        float Cf_own = (cur.rij_own < CUTOFF_F)
                     ? 0.5f * (__cosf(cur.rij_own * PI_OVER_CUTOFF) + 1.0f) : 0.0f;
        float Cf[4]; int de4[4];
        #pragma unroll
        for (int r = 0; r < 4; ++r) {
            Cf[r]  = __shfl(Cf_own, (kgrp << 2) + r);
            de4[r] = __shfl(cur.de_own, (kgrp << 2) + r);
        }

        int d0 = __shfl(cur.de_own, 0);
        bool uni = __all(cur.de_own == d0);

        if (uni) {
            const size_t dbase = (size_t)d0 * FDIM;
            #pragma unroll
            for (int n = 0; n < 8; ++n) {
                float s = 0.f;
                #pragma unroll
                for (int r = 0; r < 4; ++r)
                    s += (float)xv4[r][n] * (acc[n][r] + b2r[n]) * Cf[r];
                s += __shfl_xor(s, 16);
                s += __shfl_xor(s, 32);
                if (kgrp == 0) unsafeAtomicAdd(&agg[dbase + (n << 4) + lrow], s);
            }
        } else {
            const bool brk0 = (de4[0] != de4[1]);
            const bool brk1 = (de4[1] != de4[2]);
            const bool brk2 = (de4[2] != de4[3]);
            #pragma unroll
            for (int n = 0; n < 8; ++n) {
                int col = (n << 4) + lrow;
                float m[4];
                #pragma unroll
                for (int r = 0; r < 4; ++r)
                    m[r] = (float)xv4[r][n] * (acc[n][r] + b2r[n]) * Cf[r];
                float run = m[0];
                if (brk0) { unsafeAtomicAdd(&agg[(size_t)de4[0] * FDIM + col], run); run = 0.f; }
                run += m[1];
                if (brk1) { unsafeAtomicAdd(&agg[(size_t)de4[1] * FDIM + col], run); run = 0.f; }
                run += m[2];
                if (brk2) { unsafeAtomicAdd(&agg[(size_t)de4[2] * FDIM + col], run); run = 0.f; }
                run += m[3];
                unsafeAtomicAdd(&agg[(size_t)de4[3] * FDIM + col], run);
            }
        }

        pvB = pvC;
        cur = nxt;
    }
    #undef GATHER
}

extern "C" void kernel_launch(void* const* d_in, const int* in_sizes, int n_in,
                              void* d_out, int out_size, void* d_ws, size_t ws_size,
                              hipStream_t stream)
{
    const float* feat   = (const float*)d_in[0];
    const float* fij    = (const float*)d_in[1];
    const float* rij    = (const float*)d_in[2];
    const int*   src    = (const int*)d_in[3];
    const int*   dst    = (const int*)d_in[4];
    const float* W_in2f = (const float*)d_in[5];
    const float* W_f1   = (const float*)d_in[6];
    const float* b_f1   = (const float*)d_in[7];
    const float* W_f2   = (const float*)d_in[8];
    const float* b_f2   = (const float*)d_in[9];
    const float* W_out  = (const float*)d_in[10];
    const float* b_out  = (const float*)d_in[11];
    float* out = (float*)d_out;

    // ws layout, total 19,707,520 B (under the proven ~19.65-25.6 MB range)
    char* ws = (char*)d_ws;
    __bf16* xb       = (__bf16*)ws;                   // 12,800,000 B
    __bf16* w1p      = (__bf16*)(ws + 12800000);      //      8,192 B
    __bf16* w2p      = (__bf16*)(ws + 12808192);      //     32,768 B
    __bf16* winp     = (__bf16*)(ws + 12840960);      //     32,768 B
    __bf16* woutp    = (__bf16*)(ws + 12873728);      //     32,768 B
    int*    cursor   = (int*)(ws + 12906496);         //    200,000 B
    int*    count    = (int*)(ws + 13106496);         //    200,000 B
    int*    chunksum = (int*)(ws + 13306496);         //      1,024 B
    int*    perm     = (int*)(ws + 13307520);         //  6,400,000 B
    float*  agg      = out;                           // accumulate into d_out

    hipMemsetAsync(agg, 0, (size_t)N_ATOMS * FDIM * sizeof(float), stream);
    hipMemsetAsync(count, 0, N_ATOMS * sizeof(int), stream);

    hist_kernel<<<(N_EDGES + 255) / 256, 256, 0, stream>>>(dst, count);
    scan_chunk_kernel<<<NCH, 256, 0, stream>>>(count, chunksum);
    scan_base_kernel<<<1, 256, 0, stream>>>(chunksum);
    scan_apply_kernel<<<NCH, 256, 0, stream>>>(count, chunksum, cursor);
    scatter_kernel<<<(N_EDGES + 255) / 256, 256, 0, stream>>>(dst, cursor, perm);

    pack_b_kernel<<<(4096 + 255) / 256, 256, 0, stream>>>(W_f1, w1p, NB, 1);
    pack_b_kernel<<<(16384 + 255) / 256, 256, 0, stream>>>(W_f2, w2p, 128, 4);
    pack_b_kernel<<<(16384 + 255) / 256, 256, 0, stream>>>(W_in2f, winp, 128, 4);
    pack_b_kernel<<<(16384 + 255) / 256, 256, 0, stream>>>(W_out, woutp, 128, 4);

    // x = feat @ W_in2f  -> xb (bf16, permuted)
    node_mfma_kernel<<<(N_ATOMS / 16 + 7) / 8, 512, 0, stream>>>(
        feat, winp, nullptr, xb, nullptr, 0);

    edge_kernel<<<NBLK, 512, 0, stream>>>(
        fij, rij, src, dst, perm, w1p, b_f1, w2p, b_f2, xb, agg);

    // out = swish(agg @ W_out + b_out)  (in-place per 16-row tile)
    node_mfma_kernel<<<(N_ATOMS / 16 + 7) / 8, 512, 0, stream>>>(
        agg, woutp, b_out, nullptr, out, 1);
}